// Round 7
// baseline (522.365 us; speedup 1.0000x reference)
//
#include <hip/hip_runtime.h>

typedef unsigned short u16;
typedef short bf16x8 __attribute__((ext_vector_type(8)));
typedef float f32x4 __attribute__((ext_vector_type(4)));
typedef unsigned short u16x4 __attribute__((ext_vector_type(4)));

// B=2, T=2048, D=2048, H=16, dk=128, BH=32, M=B*T=4096
#define QK_SCALE 0.08838834764831845f

__device__ __forceinline__ u16 f2bf(float f) {
  unsigned u = __float_as_uint(f);
  u += 0x7fffu + ((u >> 16) & 1u);
  return (u16)(u >> 16);
}
__device__ __forceinline__ float bf2f(u16 h) { return __uint_as_float(((unsigned)h) << 16); }

__device__ __forceinline__ void gld_lds16(const u16* g, u16* l) {
  __builtin_amdgcn_global_load_lds(
      (const __attribute__((address_space(1))) void*)g,
      (__attribute__((address_space(3))) void*)l, 16, 0, 0);
}

// ---------------- f32 -> bf16 convert ----------------
__global__ void cvt_bf16_kernel(const float* __restrict__ in, u16* __restrict__ out, int n4) {
  int i = blockIdx.x * 256 + threadIdx.x;
  if (i >= n4) return;
  const float4 v = reinterpret_cast<const float4*>(in)[i];
  u16x4 o;
  o[0] = f2bf(v.x); o[1] = f2bf(v.y); o[2] = f2bf(v.z); o[3] = f2bf(v.w);
  reinterpret_cast<u16x4*>(out)[i] = o;
}

// ---------------- rotary folded into Q/K weight rows (bug-faithful: angle = h*freqs[j]) --------
__global__ void rotw_kernel(const float* __restrict__ w, u16* __restrict__ wb) {
  const int i = blockIdx.x * 256 + threadIdx.x;   // which(2)*h(16)*j(64)*k4(512)
  const int k4 = i & 511;
  const int j = (i >> 9) & 63;
  const int h = (i >> 15) & 15;
  const int which = i >> 19;                       // 0=Q, 1=K
  const size_t e1 = (size_t)which * 2048 + h * 128 + j;
  const size_t e2 = e1 + 64;
  const float fr = (j < 32) ? __expf(-0.2971077539f * (float)j) : 0.0f;  // (1e-4)^(j/31)
  float s, c;
  __sincosf((float)h * fr, &s, &c);
  const float scale = (which == 0) ? QK_SCALE : 1.0f;
  const float4 a = reinterpret_cast<const float4*>(w + e1 * 2048)[k4];
  const float4 b = reinterpret_cast<const float4*>(w + e2 * 2048)[k4];
  u16x4 o1, o2;
  o1[0] = f2bf((a.x * c + b.x * s) * scale);
  o1[1] = f2bf((a.y * c + b.y * s) * scale);
  o1[2] = f2bf((a.z * c + b.z * s) * scale);
  o1[3] = f2bf((a.w * c + b.w * s) * scale);
  o2[0] = f2bf((b.x * c - a.x * s) * scale);
  o2[1] = f2bf((b.y * c - a.y * s) * scale);
  o2[2] = f2bf((b.z * c - a.z * s) * scale);
  o2[3] = f2bf((b.w * c - a.w * s) * scale);
  reinterpret_cast<u16x4*>(wb + e1 * 2048)[k4] = o1;
  reinterpret_cast<u16x4*>(wb + e2 * 2048)[k4] = o2;
}

// ================= QKV GEMM: 128x384 tile, BK=32, 64KB LDS -> 2 blocks/CU, 512 blocks full fill =========
// 512 thr = 8 waves (2Mx4N), per wave 64x96 = 4x6 frags. 3 phases/K-tile (8 MFMA each),
// all cur-buf reads done by ph2 barrier -> ph3 stages t+2 into buf[cur] (race-free),
// vmcnt(4) at tile end (t+1 drained, t+2 in flight). Chunk-XOR swizzle (row&3) both sides.
// Scatter epilogue -> Q/K/V (B,H,T,dk) bf16.
__global__ __launch_bounds__(512, 4) void gemmqkv_kernel(
    const u16* __restrict__ A, const u16* __restrict__ Bw, int Kdim,
    u16* __restrict__ q_out, u16* __restrict__ k_out, u16* __restrict__ v_out)
{
  __shared__ __align__(16) u16 As[2][128 * 32];
  __shared__ __align__(16) u16 Bs[2][384 * 32];
  const int t = threadIdx.x, lane = t & 63, w = t >> 6;
  const int wr = w >> 2, wc = w & 3;
  const int l15 = lane & 15, lhi = lane >> 4;
  const int m0 = blockIdx.x * 128, n0 = blockIdx.y * 384;
  const int NT = Kdim >> 5;                       // 64 K-tiles of 32

  // staging: one issue = 512 lanes x 16B = 128 rows of 64B; LDS linear, global pre-swizzled
  const int srow = t >> 2;                         // row within 128-row issue block
  const size_t gcol = (size_t)(((lane & 3) ^ ((lane >> 2) & 3)) * 8);

  auto stage = [&](int buf, int kt) {
    const size_t kb = (size_t)kt * 32 + gcol;
    gld_lds16(A + (size_t)(m0 + srow) * Kdim + kb, &As[buf][w * 512]);
    gld_lds16(Bw + (size_t)(n0 + srow) * Kdim + kb, &Bs[buf][w * 512]);
    gld_lds16(Bw + (size_t)(n0 + 128 + srow) * Kdim + kb, &Bs[buf][4096 + w * 512]);
    gld_lds16(Bw + (size_t)(n0 + 256 + srow) * Kdim + kb, &Bs[buf][8192 + w * 512]);
  };

  // ds_read addressing (swizzled): frag row r, k-chunk lhi -> u16 off = r*32 + ((lhi^(r&3))*8)
  const int arow = (wr * 64 + l15) * 32;
  const int brow = (wc * 96 + l15) * 32;
  const int koff = (lhi ^ (l15 & 3)) * 8;

  f32x4 acc[4][6];
#pragma unroll
  for (int m = 0; m < 4; ++m)
#pragma unroll
    for (int n = 0; n < 6; ++n)
#pragma unroll
      for (int i = 0; i < 4; ++i) acc[m][n][i] = 0.0f;

  stage(0, 0);
  stage(1, 1);
  asm volatile("s_waitcnt vmcnt(4)" ::: "memory");
  __builtin_amdgcn_s_barrier();

  for (int kt = 0; kt < NT; ++kt) {
    const int cur = kt & 1;
    const u16* __restrict__ Ac = &As[cur][0];
    const u16* __restrict__ Bc = &Bs[cur][0];
    bf16x8 a[4], b[6];
    // ph1: read A0-3, B0-2 (7 ds); MFMA n0,n1
#pragma unroll
    for (int m = 0; m < 4; ++m)
      a[m] = *reinterpret_cast<const bf16x8*>(Ac + arow + m * 512 + koff);
#pragma unroll
    for (int n = 0; n < 3; ++n)
      b[n] = *reinterpret_cast<const bf16x8*>(Bc + brow + n * 512 + koff);
    __builtin_amdgcn_s_barrier();
    asm volatile("s_waitcnt lgkmcnt(0)" ::: "memory");
    __builtin_amdgcn_s_setprio(1);
#pragma unroll
    for (int m = 0; m < 4; ++m)
#pragma unroll
      for (int n = 0; n < 2; ++n)
        acc[m][n] = __builtin_amdgcn_mfma_f32_16x16x32_bf16(a[m], b[n], acc[m][n], 0, 0, 0);
    __builtin_amdgcn_s_setprio(0);
    __builtin_amdgcn_s_barrier();
    // ph2: read B3-5 (3 ds); MFMA n2,n3
#pragma unroll
    for (int n = 3; n < 6; ++n)
      b[n] = *reinterpret_cast<const bf16x8*>(Bc + brow + n * 512 + koff);
    __builtin_amdgcn_s_barrier();
    asm volatile("s_waitcnt lgkmcnt(0)" ::: "memory");
    __builtin_amdgcn_s_setprio(1);
#pragma unroll
    for (int m = 0; m < 4; ++m)
#pragma unroll
      for (int n = 2; n < 4; ++n)
        acc[m][n] = __builtin_amdgcn_mfma_f32_16x16x32_bf16(a[m], b[n], acc[m][n], 0, 0, 0);
    __builtin_amdgcn_s_setprio(0);
    __builtin_amdgcn_s_barrier();
    // ph3: all cur reads complete across waves -> stage t+2 into buf[cur]; MFMA n4,n5; counted vmcnt
    if (kt + 2 < NT) stage(cur, kt + 2);
    __builtin_amdgcn_s_setprio(1);
#pragma unroll
    for (int m = 0; m < 4; ++m)
#pragma unroll
      for (int n = 4; n < 6; ++n)
        acc[m][n] = __builtin_amdgcn_mfma_f32_16x16x32_bf16(a[m], b[n], acc[m][n], 0, 0, 0);
    __builtin_amdgcn_s_setprio(0);
    if (kt + 2 < NT) { asm volatile("s_waitcnt vmcnt(4)" ::: "memory"); }
    else             { asm volatile("s_waitcnt vmcnt(0)" ::: "memory"); }
    __builtin_amdgcn_s_barrier();
  }

  // epilogue: row = m0 + wr*64 + m*16 + lhi*4 + r ; col = n0 + wc*96 + n*16 + l15
  const int rb = wr * 64 + lhi * 4;
  const int cb = wc * 96 + l15;
#pragma unroll
  for (int n = 0; n < 6; ++n) {
    const int e = n0 + cb + n * 16;               // col in [0,6144): (which, h, d)
    const int which = e >> 11;
    const int h = (e >> 7) & 15;
    const int d = e & 127;
    u16* dst = (which == 0) ? q_out : (which == 1) ? k_out : v_out;
#pragma unroll
    for (int m = 0; m < 4; ++m)
#pragma unroll
      for (int r = 0; r < 4; ++r) {
        const int bt = m0 + rb + m * 16 + r;
        const int bb = bt >> 11, tt = bt & 2047;
        dst[((size_t)(bb * 16 + h) * 2048 + tt) * 128 + d] = f2bf(acc[m][n][r]);
      }
  }
}

// ---------------- m97-structure 128x128 GEMM (out-projection) ----------------
__global__ __launch_bounds__(256) void gemm_bt_kernel(
    const u16* __restrict__ A, const u16* __restrict__ Bw, int Kdim, int n_out,
    float* __restrict__ f_out)
{
  __shared__ __align__(16) u16 Asl[128 * 32];
  __shared__ __align__(16) u16 Bsl[128 * 32];
  const int t = threadIdx.x;
  const int lane = t & 63;
  const int w = t >> 6;
  const int wr = w >> 1, wc = w & 1;
  const int m0 = blockIdx.x * 128, n0 = blockIdx.y * 128;

  f32x4 acc[4][4];
#pragma unroll
  for (int m = 0; m < 4; ++m)
#pragma unroll
    for (int n = 0; n < 4; ++n)
#pragma unroll
      for (int i = 0; i < 4; ++i) acc[m][n][i] = 0.0f;

  const int ob0 = w * 1024 + lane * 16;
  const int row0 = ob0 >> 6;
  const int cole0 = (ob0 & 63) >> 1;
  const u16* gA0 = A + (size_t)(m0 + row0) * Kdim + cole0;
  const u16* gA1 = gA0 + (size_t)64 * Kdim;
  const u16* gB0 = Bw + (size_t)(n0 + row0) * Kdim + cole0;
  const u16* gB1 = gB0 + (size_t)64 * Kdim;
  u16* lA = Asl + w * 512;
  u16* lB = Bsl + w * 512;

  const int l15 = lane & 15;
  const int kb = (lane >> 4) * 8;

  for (int k0 = 0; k0 < Kdim; k0 += 32) {
    __syncthreads();
    gld_lds16(gA0, lA);
    gld_lds16(gA1, lA + 2048);
    gld_lds16(gB0, lB);
    gld_lds16(gB1, lB + 2048);
    gA0 += 32; gA1 += 32; gB0 += 32; gB1 += 32;
    __syncthreads();
    bf16x8 a[4], b[4];
#pragma unroll
    for (int m = 0; m < 4; ++m)
      a[m] = *reinterpret_cast<const bf16x8*>(Asl + (wr * 64 + m * 16 + l15) * 32 + kb);
#pragma unroll
    for (int n = 0; n < 4; ++n)
      b[n] = *reinterpret_cast<const bf16x8*>(Bsl + (wc * 64 + n * 16 + l15) * 32 + kb);
#pragma unroll
    for (int m = 0; m < 4; ++m)
#pragma unroll
      for (int n = 0; n < 4; ++n)
        acc[m][n] = __builtin_amdgcn_mfma_f32_16x16x32_bf16(a[m], b[n], acc[m][n], 0, 0, 0);
  }

  const int rb = wr * 64 + ((lane >> 4) << 2);
  const int cbs = wc * 64 + l15;
#pragma unroll
  for (int m = 0; m < 4; ++m)
#pragma unroll
    for (int r = 0; r < 4; ++r) {
      const int row = m0 + rb + m * 16 + r;
#pragma unroll
      for (int n = 0; n < 4; ++n)
        f_out[(size_t)row * n_out + n0 + cbs + n * 16] = acc[m][n][r];
    }
}

// ---------------- V transpose: (bh, t, d) -> (bh, d, t) ----------------
__global__ void transpose_v_kernel(const u16* __restrict__ V, u16* __restrict__ Vt) {
  __shared__ u16 tile[64][65];
  const int d0 = blockIdx.x * 64;
  const int t0 = blockIdx.y * 64;
  const int bh = blockIdx.z;
  const u16* src = V + (size_t)bh * (2048 * 128);
  u16* dst = Vt + (size_t)bh * (128 * 2048);
  const int tid = threadIdx.x;
  const int c4 = (tid & 15) * 4;
  const int r0 = tid >> 4;
#pragma unroll
  for (int p = 0; p < 4; ++p) {
    const int row = r0 + p * 16;
    const u16x4 v = *reinterpret_cast<const u16x4*>(src + (size_t)(t0 + row) * 128 + d0 + c4);
    tile[row][c4] = v[0]; tile[row][c4 + 1] = v[1];
    tile[row][c4 + 2] = v[2]; tile[row][c4 + 3] = v[3];
  }
  __syncthreads();
#pragma unroll
  for (int p = 0; p < 4; ++p) {
    const int dr = r0 + p * 16;
    u16x4 ov;
    ov[0] = tile[c4][dr]; ov[1] = tile[c4 + 1][dr];
    ov[2] = tile[c4 + 2][dr]; ov[3] = tile[c4 + 3][dr];
    *reinterpret_cast<u16x4*>(dst + (size_t)(d0 + dr) * 2048 + t0 + c4) = ov;
  }
}

// ---------------- flash attention, LDS-staged K/V, double-buffered, load-balanced ----------------
__global__ __launch_bounds__(256) void attn_kernel(
    const u16* __restrict__ Q, const u16* __restrict__ K,
    const u16* __restrict__ Vt, u16* __restrict__ O)
{
  __shared__ __align__(16) u16 k_lds[2][64 * 128];
  __shared__ __align__(16) u16 v_lds[2][128 * 64];
  __shared__ __align__(16) u16 p_lds[4][1024];
  const int t = threadIdx.x, lane = t & 63, w = t >> 6;
  const int bh = blockIdx.y;
  const int bx = blockIdx.x;
  const int l15 = lane & 15, lhi = lane >> 4;
  const size_t qkb = (size_t)bh * (2048 * 128);
  const u16* Kg = K + qkb;
  const u16* Vg = Vt + (size_t)bh * (size_t)(128 * 2048);
  char* pw = (char*)(&p_lds[w][0]);
  const int bb = bh >> 4, h = bh & 15;
  const int kxor = (l15 & 7) << 4;

  auto stage = [&](int buf, int k0) {
#pragma unroll
    for (int ii = 0; ii < 4; ++ii) {
      const int i = w * 4 + ii;
      const int krow = i * 4 + lhi;
      gld_lds16(Kg + (size_t)(k0 + krow) * 128 + (size_t)((l15 ^ (krow & 7)) * 8),
                &k_lds[buf][i * 512]);
    }
#pragma unroll
    for (int ii = 0; ii < 4; ++ii) {
      const int i = w * 4 + ii;
      const int vrow = i * 8 + (lane >> 3);
      gld_lds16(Vg + (size_t)vrow * 2048 + k0 + (size_t)(((lane & 7) ^ (vrow & 7)) * 8),
                &v_lds[buf][i * 512]);
    }
  };

  for (int half = 0; half < 2; ++half) {
    const int qt = half ? (31 - bx) : bx;
    const int q0 = qt * 64 + w * 16;
    bf16x8 aq[4];
    {
      const u16* qp = Q + qkb + (size_t)(q0 + l15) * 128 + lhi * 8;
#pragma unroll
      for (int ks = 0; ks < 4; ++ks) aq[ks] = *reinterpret_cast<const bf16x8*>(qp + ks * 32);
    }
    f32x4 o[8];
#pragma unroll
    for (int dt = 0; dt < 8; ++dt)
#pragma unroll
      for (int i = 0; i < 4; ++i) o[dt][i] = 0.0f;
    float mrow[4] = {-1e30f, -1e30f, -1e30f, -1e30f};
    float lrow[4] = {0.f, 0.f, 0.f, 0.f};
    const int rbase = q0 + (lhi << 2);
    const int ktmax = qt;

    __syncthreads();
    stage(0, 0);
    int cur = 0;
    for (int kt = 0; kt <= ktmax; ++kt) {
      __syncthreads();
      if (kt < ktmax) stage(cur ^ 1, (kt + 1) * 64);

      const char* kbb = (const char*)(&k_lds[cur][0]);
      f32x4 s4[4];
#pragma unroll
      for (int nt = 0; nt < 4; ++nt)
#pragma unroll
        for (int i = 0; i < 4; ++i) s4[nt][i] = 0.0f;
#pragma unroll
      for (int nt = 0; nt < 4; ++nt) {
        const int krow = nt * 16 + l15;
#pragma unroll
        for (int ks = 0; ks < 4; ++ks) {
          const bf16x8 bk = *reinterpret_cast<const bf16x8*>(
              kbb + krow * 256 + ((ks * 64 + lhi * 16) ^ kxor));
          s4[nt] = __builtin_amdgcn_mfma_f32_16x16x32_bf16(aq[ks], bk, s4[nt], 0, 0, 0);
        }
      }
      if (kt == ktmax) {
#pragma unroll
        for (int nt = 0; nt < 4; ++nt) {
          const int col = kt * 64 + nt * 16 + l15;
#pragma unroll
          for (int r = 0; r < 4; ++r)
            if (col > rbase + r) s4[nt][r] = -1e30f;
        }
      }
      float alpha[4];
#pragma unroll
      for (int r = 0; r < 4; ++r) {
        float mx = fmaxf(fmaxf(s4[0][r], s4[1][r]), fmaxf(s4[2][r], s4[3][r]));
        mx = fmaxf(mx, __shfl_xor(mx, 1));
        mx = fmaxf(mx, __shfl_xor(mx, 2));
        mx = fmaxf(mx, __shfl_xor(mx, 4));
        mx = fmaxf(mx, __shfl_xor(mx, 8));
        const float mn = fmaxf(mrow[r], mx);
        alpha[r] = __expf(mrow[r] - mn);
        mrow[r] = mn;
      }
      float ps[4] = {0.f, 0.f, 0.f, 0.f};
#pragma unroll
      for (int nt = 0; nt < 4; ++nt)
#pragma unroll
        for (int r = 0; r < 4; ++r) {
          const float p = __expf(s4[nt][r] - mrow[r]);
          ps[r] += p;
          const int prow = (lhi << 2) + r;
          const int cbyte = (nt * 16 + l15) * 2;
          *(u16*)(pw + prow * 128 + (cbyte ^ ((prow & 7) << 4))) = f2bf(p);
        }
#pragma unroll
      for (int r = 0; r < 4; ++r) {
        float rs = ps[r];
        rs += __shfl_xor(rs, 1);
        rs += __shfl_xor(rs, 2);
        rs += __shfl_xor(rs, 4);
        rs += __shfl_xor(rs, 8);
        lrow[r] = lrow[r] * alpha[r] + rs;
#pragma unroll
        for (int dt = 0; dt < 8; ++dt) o[dt][r] *= alpha[r];
      }
      const char* vbb = (const char*)(&v_lds[cur][0]);
#pragma unroll
      for (int ks2 = 0; ks2 < 2; ++ks2) {
        const bf16x8 ap = *reinterpret_cast<const bf16x8*>(
            pw + l15 * 128 + ((ks2 * 64 + (lhi << 4)) ^ kxor));
#pragma unroll
        for (int dt = 0; dt < 8; ++dt) {
          const int vrow = dt * 16 + l15;
          const bf16x8 bv = *reinterpret_cast<const bf16x8*>(
              vbb + vrow * 128 + ((ks2 * 64 + lhi * 16) ^ kxor));
          o[dt] = __builtin_amdgcn_mfma_f32_16x16x32_bf16(ap, bv, o[dt], 0, 0, 0);
        }
      }
      cur ^= 1;
    }
#pragma unroll
    for (int r = 0; r < 4; ++r) {
      const float inv = 1.0f / lrow[r];
      const int row = rbase + r;
      u16* op = O + (size_t)(bb * 2048 + row) * 2048 + h * 128 + l15;
#pragma unroll
      for (int dt = 0; dt < 8; ++dt) op[dt * 16] = f2bf(o[dt][r] * inv);
    }
  }
}

extern "C" void kernel_launch(void* const* d_in, const int* in_sizes, int n_in,
                              void* d_out, int out_size, void* d_ws, size_t ws_size,
                              hipStream_t stream) {
  const float* x = (const float*)d_in[0];      // (2,2048,2048) f32
  const float* wqkv = (const float*)d_in[1];   // (6144,2048) f32
  const float* wo = (const float*)d_in[2];     // (2048,2048) f32
  float* out = (float*)d_out;                  // (2,2048,2048) f32
  u16* ws = (u16*)d_ws;

  u16* xb = ws;                    // 8,388,608 elems
  u16* wqkvb = xb + 8388608;       // 12,582,912 (rotary-folded Q/K rows + plain V rows)
  u16* wob = wqkvb + 12582912;     // 4,194,304
  u16* Qb = wob + 4194304;         // 8,388,608
  u16* Kb = Qb + 8388608;          // 8,388,608
  u16* Vb = Kb + 8388608;          // 8,388,608  (total ~100.7 MB)
  u16* Vtb = wqkvb;                // alias: wqkvb dead after QKV GEMM
  u16* attn = xb;                  // alias: xb dead after QKV GEMM

  cvt_bf16_kernel<<<8192, 256, 0, stream>>>(x, xb, 2097152);
  rotw_kernel<<<4096, 256, 0, stream>>>(wqkv, wqkvb);
  cvt_bf16_kernel<<<4096, 256, 0, stream>>>(wqkv + (size_t)4096 * 2048,
                                            wqkvb + (size_t)4096 * 2048, 1048576);
  cvt_bf16_kernel<<<4096, 256, 0, stream>>>(wo, wob, 1048576);

  // QKV: M=4096, N=6144, K=2048 -> scatter to Q/K/V (B,H,T,dk) bf16 (rotary pre-folded)
  // 128x384 tiles: 32x16 = 512 blocks = 2/CU, full fill single generation
  gemmqkv_kernel<<<dim3(32, 16), 512, 0, stream>>>(xb, wqkvb, 2048, Qb, Kb, Vb);

  transpose_v_kernel<<<dim3(2, 32, 32), 256, 0, stream>>>(Vb, Vtb);

  attn_kernel<<<dim3(16, 32), 256, 0, stream>>>(Qb, Kb, Vtb, attn);

  // Out proj: M=4096, N=2048, K=2048 -> f32 d_out
  gemm_bt_kernel<<<dim3(32, 16), 256, 0, stream>>>(attn, wob, 2048, 2048, out);
}

// Round 8
// 363.660 us; speedup vs baseline: 1.4364x; 1.4364x over previous
//
#include <hip/hip_runtime.h>

typedef unsigned short u16;
typedef short bf16x8 __attribute__((ext_vector_type(8)));
typedef float f32x4 __attribute__((ext_vector_type(4)));
typedef unsigned short u16x4 __attribute__((ext_vector_type(4)));

// B=2, T=2048, D=2048, H=16, dk=128, BH=32, M=B*T=4096
#define QK_SCALE 0.08838834764831845f

__device__ __forceinline__ u16 f2bf(float f) {
  unsigned u = __float_as_uint(f);
  u += 0x7fffu + ((u >> 16) & 1u);
  return (u16)(u >> 16);
}
__device__ __forceinline__ float bf2f(u16 h) { return __uint_as_float(((unsigned)h) << 16); }

__device__ __forceinline__ void gld_lds16(const u16* g, u16* l) {
  __builtin_amdgcn_global_load_lds(
      (const __attribute__((address_space(1))) void*)g,
      (__attribute__((address_space(3))) void*)l, 16, 0, 0);
}

// ---------------- f32 -> bf16 convert ----------------
__global__ void cvt_bf16_kernel(const float* __restrict__ in, u16* __restrict__ out, int n4) {
  int i = blockIdx.x * 256 + threadIdx.x;
  if (i >= n4) return;
  const float4 v = reinterpret_cast<const float4*>(in)[i];
  u16x4 o;
  o[0] = f2bf(v.x); o[1] = f2bf(v.y); o[2] = f2bf(v.z); o[3] = f2bf(v.w);
  reinterpret_cast<u16x4*>(out)[i] = o;
}

// ---------------- rotary folded into Q/K weight rows (bug-faithful: angle = h*freqs[j]) --------
__global__ void rotw_kernel(const float* __restrict__ w, u16* __restrict__ wb) {
  const int i = blockIdx.x * 256 + threadIdx.x;   // which(2)*h(16)*j(64)*k4(512)
  const int k4 = i & 511;
  const int j = (i >> 9) & 63;
  const int h = (i >> 15) & 15;
  const int which = i >> 19;                       // 0=Q, 1=K
  const size_t e1 = (size_t)which * 2048 + h * 128 + j;
  const size_t e2 = e1 + 64;
  const float fr = (j < 32) ? __expf(-0.2971077539f * (float)j) : 0.0f;  // (1e-4)^(j/31)
  float s, c;
  __sincosf((float)h * fr, &s, &c);
  const float scale = (which == 0) ? QK_SCALE : 1.0f;
  const float4 a = reinterpret_cast<const float4*>(w + e1 * 2048)[k4];
  const float4 b = reinterpret_cast<const float4*>(w + e2 * 2048)[k4];
  u16x4 o1, o2;
  o1[0] = f2bf((a.x * c + b.x * s) * scale);
  o1[1] = f2bf((a.y * c + b.y * s) * scale);
  o1[2] = f2bf((a.z * c + b.z * s) * scale);
  o1[3] = f2bf((a.w * c + b.w * s) * scale);
  o2[0] = f2bf((b.x * c - a.x * s) * scale);
  o2[1] = f2bf((b.y * c - a.y * s) * scale);
  o2[2] = f2bf((b.z * c - a.z * s) * scale);
  o2[3] = f2bf((b.w * c - a.w * s) * scale);
  reinterpret_cast<u16x4*>(wb + e1 * 2048)[k4] = o1;
  reinterpret_cast<u16x4*>(wb + e2 * 2048)[k4] = o2;
}

// ================= 256x256 8-phase GEMM (round-3/6 proven config), C=A*Bw^T =================
template<int MODE>
__global__ __launch_bounds__(512, 2) void gemm8p_kernel(
    const u16* __restrict__ A, const u16* __restrict__ Bw, int Kdim, int n_out,
    u16* __restrict__ q_out, u16* __restrict__ k_out, u16* __restrict__ v_out,
    float* __restrict__ f_out)
{
  __shared__ __align__(16) u16 As[2][256 * 64];
  __shared__ __align__(16) u16 Bs[2][256 * 64];
  const int t = threadIdx.x, lane = t & 63, w = t >> 6;
  const int wr = w >> 2, wc = w & 3;
  const int l15 = lane & 15, lhi = lane >> 4;
  const int m0 = blockIdx.x * 256, n0 = blockIdx.y * 256;
  const int NT = Kdim >> 6;

  const int srow = w * 8 + (lane >> 3);
  const int gchunk = (lane & 7) ^ (srow & 7);
  const size_t gcol = (size_t)gchunk * 8;

  auto stageA2 = [&](int buf, int kt2, int half) {
    const size_t kb = (size_t)kt2 * 64 + gcol;
#pragma unroll
    for (int i = 0; i < 2; ++i) {
      const int ro = half * 128 + i * 64;
      gld_lds16(A + (size_t)(m0 + srow + ro) * Kdim + kb, &As[buf][(w * 8 + ro) * 64]);
    }
  };
  auto stageB4 = [&](int buf, int kt2) {
    const size_t kb = (size_t)kt2 * 64 + gcol;
#pragma unroll
    for (int ro = 0; ro < 256; ro += 64)
      gld_lds16(Bw + (size_t)(n0 + srow + ro) * Kdim + kb, &Bs[buf][(w * 8 + ro) * 64]);
  };

  const int arow0 = (wr * 128 + l15) * 64;
  const int brow0 = (wc * 64 + l15) * 64;
  const int koff0 = ((0 + lhi) ^ (l15 & 7)) * 8;
  const int koff1 = ((4 + lhi) ^ (l15 & 7)) * 8;

  f32x4 acc[8][4];
#pragma unroll
  for (int m = 0; m < 8; ++m)
#pragma unroll
    for (int n = 0; n < 4; ++n)
#pragma unroll
      for (int i = 0; i < 4; ++i) acc[m][n][i] = 0.0f;

  stageA2(0, 0, 0); stageA2(0, 0, 1);
  stageB4(0, 0);
  if (NT > 1) { stageA2(1, 1, 0); stageA2(1, 1, 1); }
  asm volatile("s_waitcnt vmcnt(4)" ::: "memory");
  __builtin_amdgcn_s_barrier();

  for (int kt = 0; kt < NT; ++kt) {
    const int cur = kt & 1;
    const u16* __restrict__ Ac = &As[cur][0];
    const u16* __restrict__ Bc = &Bs[cur][0];
    bf16x8 aK1[4], a2K1[4], b0[4], b1[4];
    // P1: read A[m0-3] k0+k1, B k0; stage B(t+1); MFMA m0-3 x k0
    {
      bf16x8 aK0[4];
#pragma unroll
      for (int m = 0; m < 4; ++m) {
        aK0[m] = *reinterpret_cast<const bf16x8*>(Ac + arow0 + m * 1024 + koff0);
        aK1[m] = *reinterpret_cast<const bf16x8*>(Ac + arow0 + m * 1024 + koff1);
      }
#pragma unroll
      for (int n = 0; n < 4; ++n)
        b0[n] = *reinterpret_cast<const bf16x8*>(Bc + brow0 + n * 1024 + koff0);
      if (kt + 1 < NT) stageB4(cur ^ 1, kt + 1);
      __builtin_amdgcn_s_barrier();
      asm volatile("s_waitcnt lgkmcnt(0)" ::: "memory");
      __builtin_amdgcn_s_setprio(1);
#pragma unroll
      for (int m = 0; m < 4; ++m)
#pragma unroll
        for (int n = 0; n < 4; ++n)
          acc[m][n] = __builtin_amdgcn_mfma_f32_16x16x32_bf16(aK0[m], b0[n], acc[m][n], 0, 0, 0);
      __builtin_amdgcn_s_setprio(0);
      __builtin_amdgcn_s_barrier();
    }
    // P2: read A[m4-7] k0+k1, B k1; MFMA m4-7 x k0
    {
      bf16x8 a2K0[4];
#pragma unroll
      for (int m = 0; m < 4; ++m) {
        a2K0[m] = *reinterpret_cast<const bf16x8*>(Ac + arow0 + (m + 4) * 1024 + koff0);
        a2K1[m] = *reinterpret_cast<const bf16x8*>(Ac + arow0 + (m + 4) * 1024 + koff1);
      }
#pragma unroll
      for (int n = 0; n < 4; ++n)
        b1[n] = *reinterpret_cast<const bf16x8*>(Bc + brow0 + n * 1024 + koff1);
      __builtin_amdgcn_s_barrier();
      asm volatile("s_waitcnt lgkmcnt(0)" ::: "memory");
      __builtin_amdgcn_s_setprio(1);
#pragma unroll
      for (int m = 0; m < 4; ++m)
#pragma unroll
        for (int n = 0; n < 4; ++n)
          acc[m + 4][n] = __builtin_amdgcn_mfma_f32_16x16x32_bf16(a2K0[m], b0[n], acc[m + 4][n], 0, 0, 0);
      __builtin_amdgcn_s_setprio(0);
      __builtin_amdgcn_s_barrier();
    }
    // P3: stage A(t+2) half0; MFMA m0-3 x k1
    if (kt + 2 < NT) stageA2(cur, kt + 2, 0);
    __builtin_amdgcn_s_barrier();
    __builtin_amdgcn_s_setprio(1);
#pragma unroll
    for (int m = 0; m < 4; ++m)
#pragma unroll
      for (int n = 0; n < 4; ++n)
        acc[m][n] = __builtin_amdgcn_mfma_f32_16x16x32_bf16(aK1[m], b1[n], acc[m][n], 0, 0, 0);
    __builtin_amdgcn_s_setprio(0);
    __builtin_amdgcn_s_barrier();
    // P4: stage A(t+2) half1; MFMA m4-7 x k1; counted vmcnt
    if (kt + 2 < NT) stageA2(cur, kt + 2, 1);
    __builtin_amdgcn_s_barrier();
    __builtin_amdgcn_s_setprio(1);
#pragma unroll
    for (int m = 0; m < 4; ++m)
#pragma unroll
      for (int n = 0; n < 4; ++n)
        acc[m + 4][n] = __builtin_amdgcn_mfma_f32_16x16x32_bf16(a2K1[m], b1[n], acc[m + 4][n], 0, 0, 0);
    __builtin_amdgcn_s_setprio(0);
    if (kt < NT - 2) { asm volatile("s_waitcnt vmcnt(4)" ::: "memory"); }
    else             { asm volatile("s_waitcnt vmcnt(0)" ::: "memory"); }
    __builtin_amdgcn_s_barrier();
  }

  // epilogue: row = m0 + wr*128 + m*16 + lhi*4 + r ; col = n0 + wc*64 + n*16 + l15
  const int rb = wr * 128 + lhi * 4;
  const int cb = wc * 64 + l15;
  if (MODE == 0) {
#pragma unroll
    for (int n = 0; n < 4; ++n) {
      const int e = n0 + cb + n * 16;
      const int which = e >> 11;
      const int h = (e >> 7) & 15;
      const int d = e & 127;
      u16* dst = (which == 0) ? q_out : (which == 1) ? k_out : v_out;
#pragma unroll
      for (int m = 0; m < 8; ++m)
#pragma unroll
        for (int r = 0; r < 4; ++r) {
          const int bt = m0 + rb + m * 16 + r;
          const int bb = bt >> 11, tt = bt & 2047;
          dst[((size_t)(bb * 16 + h) * 2048 + tt) * 128 + d] = f2bf(acc[m][n][r]);
        }
    }
  } else {
#pragma unroll
    for (int m = 0; m < 8; ++m)
#pragma unroll
      for (int r = 0; r < 4; ++r) {
        const int row = m0 + rb + m * 16 + r;
#pragma unroll
        for (int n = 0; n < 4; ++n)
          f_out[(size_t)row * n_out + n0 + cb + n * 16] = acc[m][n][r];
      }
  }
}

// ---------------- m97-structure 128x128 GEMM (out-projection) ----------------
__global__ __launch_bounds__(256) void gemm_bt_kernel(
    const u16* __restrict__ A, const u16* __restrict__ Bw, int Kdim, int n_out,
    float* __restrict__ f_out)
{
  __shared__ __align__(16) u16 Asl[128 * 32];
  __shared__ __align__(16) u16 Bsl[128 * 32];
  const int t = threadIdx.x;
  const int lane = t & 63;
  const int w = t >> 6;
  const int wr = w >> 1, wc = w & 1;
  const int m0 = blockIdx.x * 128, n0 = blockIdx.y * 128;

  f32x4 acc[4][4];
#pragma unroll
  for (int m = 0; m < 4; ++m)
#pragma unroll
    for (int n = 0; n < 4; ++n)
#pragma unroll
      for (int i = 0; i < 4; ++i) acc[m][n][i] = 0.0f;

  const int ob0 = w * 1024 + lane * 16;
  const int row0 = ob0 >> 6;
  const int cole0 = (ob0 & 63) >> 1;
  const u16* gA0 = A + (size_t)(m0 + row0) * Kdim + cole0;
  const u16* gA1 = gA0 + (size_t)64 * Kdim;
  const u16* gB0 = Bw + (size_t)(n0 + row0) * Kdim + cole0;
  const u16* gB1 = gB0 + (size_t)64 * Kdim;
  u16* lA = Asl + w * 512;
  u16* lB = Bsl + w * 512;

  const int l15 = lane & 15;
  const int kb = (lane >> 4) * 8;

  for (int k0 = 0; k0 < Kdim; k0 += 32) {
    __syncthreads();
    gld_lds16(gA0, lA);
    gld_lds16(gA1, lA + 2048);
    gld_lds16(gB0, lB);
    gld_lds16(gB1, lB + 2048);
    gA0 += 32; gA1 += 32; gB0 += 32; gB1 += 32;
    __syncthreads();
    bf16x8 a[4], b[4];
#pragma unroll
    for (int m = 0; m < 4; ++m)
      a[m] = *reinterpret_cast<const bf16x8*>(Asl + (wr * 64 + m * 16 + l15) * 32 + kb);
#pragma unroll
    for (int n = 0; n < 4; ++n)
      b[n] = *reinterpret_cast<const bf16x8*>(Bsl + (wc * 64 + n * 16 + l15) * 32 + kb);
#pragma unroll
    for (int m = 0; m < 4; ++m)
#pragma unroll
      for (int n = 0; n < 4; ++n)
        acc[m][n] = __builtin_amdgcn_mfma_f32_16x16x32_bf16(a[m], b[n], acc[m][n], 0, 0, 0);
  }

  const int rb = wr * 64 + ((lane >> 4) << 2);
  const int cbs = wc * 64 + l15;
#pragma unroll
  for (int m = 0; m < 4; ++m)
#pragma unroll
    for (int r = 0; r < 4; ++r) {
      const int row = m0 + rb + m * 16 + r;
#pragma unroll
      for (int n = 0; n < 4; ++n)
        f_out[(size_t)row * n_out + n0 + cbs + n * 16] = acc[m][n][r];
    }
}

// ---------------- V transpose: (bh, t, d) -> (bh, d, t) ----------------
__global__ void transpose_v_kernel(const u16* __restrict__ V, u16* __restrict__ Vt) {
  __shared__ u16 tile[64][65];
  const int d0 = blockIdx.x * 64;
  const int t0 = blockIdx.y * 64;
  const int bh = blockIdx.z;
  const u16* src = V + (size_t)bh * (2048 * 128);
  u16* dst = Vt + (size_t)bh * (128 * 2048);
  const int tid = threadIdx.x;
  const int c4 = (tid & 15) * 4;
  const int r0 = tid >> 4;
#pragma unroll
  for (int p = 0; p < 4; ++p) {
    const int row = r0 + p * 16;
    const u16x4 v = *reinterpret_cast<const u16x4*>(src + (size_t)(t0 + row) * 128 + d0 + c4);
    tile[row][c4] = v[0]; tile[row][c4 + 1] = v[1];
    tile[row][c4 + 2] = v[2]; tile[row][c4 + 3] = v[3];
  }
  __syncthreads();
#pragma unroll
  for (int p = 0; p < 4; ++p) {
    const int dr = r0 + p * 16;
    u16x4 ov;
    ov[0] = tile[c4][dr]; ov[1] = tile[c4 + 1][dr];
    ov[2] = tile[c4 + 2][dr]; ov[3] = tile[c4 + 3][dr];
    *reinterpret_cast<u16x4*>(dst + (size_t)(d0 + dr) * 2048 + t0 + c4) = ov;
  }
}

// ---------------- flash attention with K/V-prefix sharing ----------------
// Block bx owns q-tiles {qlo=bx, qhi=31-bx}. ONE kt loop 0..qhi stages each K/V tile once;
// the high tile consumes every kt, the low tile consumes kt<=qlo (its K/V stream is a prefix).
// Compute balanced (33 tile-computations/block); staging 33 -> qhi+1 tiles (avg 24.5).
__global__ __launch_bounds__(256) void attn_kernel(
    const u16* __restrict__ Q, const u16* __restrict__ K,
    const u16* __restrict__ Vt, u16* __restrict__ O)
{
  __shared__ __align__(16) u16 k_lds[2][64 * 128];
  __shared__ __align__(16) u16 v_lds[2][128 * 64];
  __shared__ __align__(16) u16 p_lds[4][1024];
  const int t = threadIdx.x, lane = t & 63, w = t >> 6;
  const int bh = blockIdx.y;
  const int bx = blockIdx.x;
  const int l15 = lane & 15, lh4 = lane >> 4;
  const size_t qkb = (size_t)bh * (2048 * 128);
  const u16* Kg = K + qkb;
  const u16* Vg = Vt + (size_t)bh * (size_t)(128 * 2048);
  char* pw = (char*)(&p_lds[w][0]);
  const int bb = bh >> 4, h = bh & 15;
  const int kxor = (l15 & 7) << 4;

  auto stage = [&](int buf, int k0) {
#pragma unroll
    for (int ii = 0; ii < 4; ++ii) {
      const int i = w * 4 + ii;
      const int krow = i * 4 + lh4;
      gld_lds16(Kg + (size_t)(k0 + krow) * 128 + (size_t)((l15 ^ (krow & 7)) * 8),
                &k_lds[buf][i * 512]);
    }
#pragma unroll
    for (int ii = 0; ii < 4; ++ii) {
      const int i = w * 4 + ii;
      const int vrow = i * 8 + (lane >> 3);
      gld_lds16(Vg + (size_t)vrow * 2048 + k0 + (size_t)(((lane & 7) ^ (vrow & 7)) * 8),
                &v_lds[buf][i * 512]);
    }
  };

  const int qlo = bx, qhi = 31 - bx;
  const int q0lo = qlo * 64 + w * 16, q0hi = qhi * 64 + w * 16;
  const int rbLo = q0lo + (lh4 << 2), rbHi = q0hi + (lh4 << 2);

  bf16x8 aqlo[4], aqhi[4];
  {
    const u16* qp = Q + qkb + (size_t)(q0lo + l15) * 128 + lh4 * 8;
#pragma unroll
    for (int ks = 0; ks < 4; ++ks) aqlo[ks] = *reinterpret_cast<const bf16x8*>(qp + ks * 32);
  }
  {
    const u16* qp = Q + qkb + (size_t)(q0hi + l15) * 128 + lh4 * 8;
#pragma unroll
    for (int ks = 0; ks < 4; ++ks) aqhi[ks] = *reinterpret_cast<const bf16x8*>(qp + ks * 32);
  }
  f32x4 olo[8], ohi[8];
#pragma unroll
  for (int dt = 0; dt < 8; ++dt)
#pragma unroll
    for (int i = 0; i < 4; ++i) { olo[dt][i] = 0.0f; ohi[dt][i] = 0.0f; }
  float mLo[4] = {-1e30f, -1e30f, -1e30f, -1e30f};
  float lLo[4] = {0.f, 0.f, 0.f, 0.f};
  float mHi[4] = {-1e30f, -1e30f, -1e30f, -1e30f};
  float lHi[4] = {0.f, 0.f, 0.f, 0.f};

#define TILE_BODY(AQ, OO, MM, LL, QT, RB) do { \
    f32x4 s4[4]; \
    _Pragma("unroll") for (int nt = 0; nt < 4; ++nt) \
      _Pragma("unroll") for (int i = 0; i < 4; ++i) s4[nt][i] = 0.0f; \
    _Pragma("unroll") for (int nt = 0; nt < 4; ++nt) { \
      const int krow = nt * 16 + l15; \
      _Pragma("unroll") for (int ks = 0; ks < 4; ++ks) { \
        const bf16x8 bk = *reinterpret_cast<const bf16x8*>( \
            kbb + krow * 256 + ((ks * 64 + lh4 * 16) ^ kxor)); \
        s4[nt] = __builtin_amdgcn_mfma_f32_16x16x32_bf16(AQ[ks], bk, s4[nt], 0, 0, 0); } } \
    if (kt == (QT)) { \
      _Pragma("unroll") for (int nt = 0; nt < 4; ++nt) { \
        const int col = kt * 64 + nt * 16 + l15; \
        _Pragma("unroll") for (int r = 0; r < 4; ++r) \
          if (col > (RB) + r) s4[nt][r] = -1e30f; } } \
    float alpha[4]; \
    _Pragma("unroll") for (int r = 0; r < 4; ++r) { \
      float mx = fmaxf(fmaxf(s4[0][r], s4[1][r]), fmaxf(s4[2][r], s4[3][r])); \
      mx = fmaxf(mx, __shfl_xor(mx, 1)); \
      mx = fmaxf(mx, __shfl_xor(mx, 2)); \
      mx = fmaxf(mx, __shfl_xor(mx, 4)); \
      mx = fmaxf(mx, __shfl_xor(mx, 8)); \
      const float mn = fmaxf(MM[r], mx); \
      alpha[r] = __expf(MM[r] - mn); \
      MM[r] = mn; } \
    float ps[4] = {0.f, 0.f, 0.f, 0.f}; \
    _Pragma("unroll") for (int nt = 0; nt < 4; ++nt) \
      _Pragma("unroll") for (int r = 0; r < 4; ++r) { \
        const float p = __expf(s4[nt][r] - MM[r]); \
        ps[r] += p; \
        const int prow = (lh4 << 2) + r; \
        const int cbyte = (nt * 16 + l15) * 2; \
        *(u16*)(pw + prow * 128 + (cbyte ^ ((prow & 7) << 4))) = f2bf(p); } \
    _Pragma("unroll") for (int r = 0; r < 4; ++r) { \
      float rs = ps[r]; \
      rs += __shfl_xor(rs, 1); \
      rs += __shfl_xor(rs, 2); \
      rs += __shfl_xor(rs, 4); \
      rs += __shfl_xor(rs, 8); \
      LL[r] = LL[r] * alpha[r] + rs; \
      _Pragma("unroll") for (int dt = 0; dt < 8; ++dt) OO[dt][r] *= alpha[r]; } \
    _Pragma("unroll") for (int ks2 = 0; ks2 < 2; ++ks2) { \
      const bf16x8 ap = *reinterpret_cast<const bf16x8*>( \
          pw + l15 * 128 + ((ks2 * 64 + (lh4 << 4)) ^ kxor)); \
      _Pragma("unroll") for (int dt = 0; dt < 8; ++dt) { \
        const int vrow = dt * 16 + l15; \
        const bf16x8 bv = *reinterpret_cast<const bf16x8*>( \
            vbb + vrow * 128 + ((ks2 * 64 + lh4 * 16) ^ kxor)); \
        OO[dt] = __builtin_amdgcn_mfma_f32_16x16x32_bf16(ap, bv, OO[dt], 0, 0, 0); } } \
  } while (0)

  stage(0, 0);
  int cur = 0;
  for (int kt = 0; kt <= qhi; ++kt) {
    __syncthreads();                 // drains vmcnt: buf[cur] ready; prev compute done
    if (kt < qhi) stage(cur ^ 1, (kt + 1) * 64);
    const char* kbb = (const char*)(&k_lds[cur][0]);
    const char* vbb = (const char*)(&v_lds[cur][0]);
    TILE_BODY(aqhi, ohi, mHi, lHi, qhi, rbHi);
    if (kt <= qlo) TILE_BODY(aqlo, olo, mLo, lLo, qlo, rbLo);
    cur ^= 1;
  }
#undef TILE_BODY

#pragma unroll
  for (int r = 0; r < 4; ++r) {
    const float invh = 1.0f / lHi[r];
    u16* oph = O + (size_t)(bb * 2048 + rbHi + r) * 2048 + h * 128 + l15;
#pragma unroll
    for (int dt = 0; dt < 8; ++dt) oph[dt * 16] = f2bf(ohi[dt][r] * invh);
    const float invl = 1.0f / lLo[r];
    u16* opl = O + (size_t)(bb * 2048 + rbLo + r) * 2048 + h * 128 + l15;
#pragma unroll
    for (int dt = 0; dt < 8; ++dt) opl[dt * 16] = f2bf(olo[dt][r] * invl);
  }
}

extern "C" void kernel_launch(void* const* d_in, const int* in_sizes, int n_in,
                              void* d_out, int out_size, void* d_ws, size_t ws_size,
                              hipStream_t stream) {
  const float* x = (const float*)d_in[0];      // (2,2048,2048) f32
  const float* wqkv = (const float*)d_in[1];   // (6144,2048) f32
  const float* wo = (const float*)d_in[2];     // (2048,2048) f32
  float* out = (float*)d_out;                  // (2,2048,2048) f32
  u16* ws = (u16*)d_ws;

  u16* xb = ws;                    // 8,388,608 elems
  u16* wqkvb = xb + 8388608;       // 12,582,912 (rotary-folded Q/K rows + plain V rows)
  u16* wob = wqkvb + 12582912;     // 4,194,304
  u16* Qb = wob + 4194304;         // 8,388,608
  u16* Kb = Qb + 8388608;          // 8,388,608
  u16* Vb = Kb + 8388608;          // 8,388,608  (total ~100.7 MB)
  u16* Vtb = wqkvb;                // alias: wqkvb dead after QKV GEMM
  u16* attn = xb;                  // alias: xb dead after QKV GEMM

  cvt_bf16_kernel<<<8192, 256, 0, stream>>>(x, xb, 2097152);
  rotw_kernel<<<4096, 256, 0, stream>>>(wqkv, wqkvb);
  cvt_bf16_kernel<<<4096, 256, 0, stream>>>(wqkv + (size_t)4096 * 2048,
                                            wqkvb + (size_t)4096 * 2048, 1048576);
  cvt_bf16_kernel<<<4096, 256, 0, stream>>>(wo, wob, 1048576);

  // QKV: M=4096, N=6144, K=2048 -> scatter to Q/K/V (B,H,T,dk) bf16 (rotary pre-folded)
  gemm8p_kernel<0><<<dim3(16, 24), 512, 0, stream>>>(xb, wqkvb, 2048, 0, Qb, Kb, Vb, nullptr);

  transpose_v_kernel<<<dim3(2, 32, 32), 256, 0, stream>>>(Vb, Vtb);

  attn_kernel<<<dim3(16, 32), 256, 0, stream>>>(Qb, Kb, Vtb, attn);

  // Out proj: M=4096, N=2048, K=2048 -> f32 d_out
  gemm_bt_kernel<<<dim3(32, 16), 256, 0, stream>>>(attn, wob, 2048, 2048, out);
}

// Round 9
// 312.029 us; speedup vs baseline: 1.6741x; 1.1655x over previous
//
#include <hip/hip_runtime.h>

typedef unsigned short u16;
typedef short bf16x8 __attribute__((ext_vector_type(8)));
typedef float f32x4 __attribute__((ext_vector_type(4)));
typedef unsigned short u16x4 __attribute__((ext_vector_type(4)));

// B=2, T=2048, D=2048, H=16, dk=128, BH=32, M=B*T=4096
#define QK_SCALE 0.08838834764831845f

__device__ __forceinline__ u16 f2bf(float f) {
  unsigned u = __float_as_uint(f);
  u += 0x7fffu + ((u >> 16) & 1u);
  return (u16)(u >> 16);
}
__device__ __forceinline__ float bf2f(u16 h) { return __uint_as_float(((unsigned)h) << 16); }

__device__ __forceinline__ void gld_lds16(const u16* g, u16* l) {
  __builtin_amdgcn_global_load_lds(
      (const __attribute__((address_space(1))) void*)g,
      (__attribute__((address_space(3))) void*)l, 16, 0, 0);
}

// ---------------- f32 -> bf16 convert ----------------
__global__ void cvt_bf16_kernel(const float* __restrict__ in, u16* __restrict__ out, int n4) {
  int i = blockIdx.x * 256 + threadIdx.x;
  if (i >= n4) return;
  const float4 v = reinterpret_cast<const float4*>(in)[i];
  u16x4 o;
  o[0] = f2bf(v.x); o[1] = f2bf(v.y); o[2] = f2bf(v.z); o[3] = f2bf(v.w);
  reinterpret_cast<u16x4*>(out)[i] = o;
}

// ---------------- rotary folded into Q/K weight rows (bug-faithful: angle = h*freqs[j]) --------
__global__ void rotw_kernel(const float* __restrict__ w, u16* __restrict__ wb) {
  const int i = blockIdx.x * 256 + threadIdx.x;   // which(2)*h(16)*j(64)*k4(512)
  const int k4 = i & 511;
  const int j = (i >> 9) & 63;
  const int h = (i >> 15) & 15;
  const int which = i >> 19;                       // 0=Q, 1=K
  const size_t e1 = (size_t)which * 2048 + h * 128 + j;
  const size_t e2 = e1 + 64;
  const float fr = (j < 32) ? __expf(-0.2971077539f * (float)j) : 0.0f;  // (1e-4)^(j/31)
  float s, c;
  __sincosf((float)h * fr, &s, &c);
  const float scale = (which == 0) ? QK_SCALE : 1.0f;
  const float4 a = reinterpret_cast<const float4*>(w + e1 * 2048)[k4];
  const float4 b = reinterpret_cast<const float4*>(w + e2 * 2048)[k4];
  u16x4 o1, o2;
  o1[0] = f2bf((a.x * c + b.x * s) * scale);
  o1[1] = f2bf((a.y * c + b.y * s) * scale);
  o1[2] = f2bf((a.z * c + b.z * s) * scale);
  o1[3] = f2bf((a.w * c + b.w * s) * scale);
  o2[0] = f2bf((b.x * c - a.x * s) * scale);
  o2[1] = f2bf((b.y * c - a.y * s) * scale);
  o2[2] = f2bf((b.z * c - a.z * s) * scale);
  o2[3] = f2bf((b.w * c - a.w * s) * scale);
  reinterpret_cast<u16x4*>(wb + e1 * 2048)[k4] = o1;
  reinterpret_cast<u16x4*>(wb + e2 * 2048)[k4] = o2;
}

// ================= 256x256 8-phase GEMM (round-3/6 proven config), C=A*Bw^T =================
template<int MODE>
__global__ __launch_bounds__(512, 2) void gemm8p_kernel(
    const u16* __restrict__ A, const u16* __restrict__ Bw, int Kdim, int n_out,
    u16* __restrict__ q_out, u16* __restrict__ k_out, u16* __restrict__ v_out,
    float* __restrict__ f_out)
{
  __shared__ __align__(16) u16 As[2][256 * 64];
  __shared__ __align__(16) u16 Bs[2][256 * 64];
  const int t = threadIdx.x, lane = t & 63, w = t >> 6;
  const int wr = w >> 2, wc = w & 3;
  const int l15 = lane & 15, lhi = lane >> 4;
  const int m0 = blockIdx.x * 256, n0 = blockIdx.y * 256;
  const int NT = Kdim >> 6;

  const int srow = w * 8 + (lane >> 3);
  const int gchunk = (lane & 7) ^ (srow & 7);
  const size_t gcol = (size_t)gchunk * 8;

  auto stageA2 = [&](int buf, int kt2, int half) {
    const size_t kb = (size_t)kt2 * 64 + gcol;
#pragma unroll
    for (int i = 0; i < 2; ++i) {
      const int ro = half * 128 + i * 64;
      gld_lds16(A + (size_t)(m0 + srow + ro) * Kdim + kb, &As[buf][(w * 8 + ro) * 64]);
    }
  };
  auto stageB4 = [&](int buf, int kt2) {
    const size_t kb = (size_t)kt2 * 64 + gcol;
#pragma unroll
    for (int ro = 0; ro < 256; ro += 64)
      gld_lds16(Bw + (size_t)(n0 + srow + ro) * Kdim + kb, &Bs[buf][(w * 8 + ro) * 64]);
  };

  const int arow0 = (wr * 128 + l15) * 64;
  const int brow0 = (wc * 64 + l15) * 64;
  const int koff0 = ((0 + lhi) ^ (l15 & 7)) * 8;
  const int koff1 = ((4 + lhi) ^ (l15 & 7)) * 8;

  f32x4 acc[8][4];
#pragma unroll
  for (int m = 0; m < 8; ++m)
#pragma unroll
    for (int n = 0; n < 4; ++n)
#pragma unroll
      for (int i = 0; i < 4; ++i) acc[m][n][i] = 0.0f;

  stageA2(0, 0, 0); stageA2(0, 0, 1);
  stageB4(0, 0);
  if (NT > 1) { stageA2(1, 1, 0); stageA2(1, 1, 1); }
  asm volatile("s_waitcnt vmcnt(4)" ::: "memory");
  __builtin_amdgcn_s_barrier();

  for (int kt = 0; kt < NT; ++kt) {
    const int cur = kt & 1;
    const u16* __restrict__ Ac = &As[cur][0];
    const u16* __restrict__ Bc = &Bs[cur][0];
    bf16x8 aK1[4], a2K1[4], b0[4], b1[4];
    // P1: read A[m0-3] k0+k1, B k0; stage B(t+1); MFMA m0-3 x k0
    {
      bf16x8 aK0[4];
#pragma unroll
      for (int m = 0; m < 4; ++m) {
        aK0[m] = *reinterpret_cast<const bf16x8*>(Ac + arow0 + m * 1024 + koff0);
        aK1[m] = *reinterpret_cast<const bf16x8*>(Ac + arow0 + m * 1024 + koff1);
      }
#pragma unroll
      for (int n = 0; n < 4; ++n)
        b0[n] = *reinterpret_cast<const bf16x8*>(Bc + brow0 + n * 1024 + koff0);
      if (kt + 1 < NT) stageB4(cur ^ 1, kt + 1);
      __builtin_amdgcn_s_barrier();
      asm volatile("s_waitcnt lgkmcnt(0)" ::: "memory");
      __builtin_amdgcn_s_setprio(1);
#pragma unroll
      for (int m = 0; m < 4; ++m)
#pragma unroll
        for (int n = 0; n < 4; ++n)
          acc[m][n] = __builtin_amdgcn_mfma_f32_16x16x32_bf16(aK0[m], b0[n], acc[m][n], 0, 0, 0);
      __builtin_amdgcn_s_setprio(0);
      __builtin_amdgcn_s_barrier();
    }
    // P2: read A[m4-7] k0+k1, B k1; MFMA m4-7 x k0
    {
      bf16x8 a2K0[4];
#pragma unroll
      for (int m = 0; m < 4; ++m) {
        a2K0[m] = *reinterpret_cast<const bf16x8*>(Ac + arow0 + (m + 4) * 1024 + koff0);
        a2K1[m] = *reinterpret_cast<const bf16x8*>(Ac + arow0 + (m + 4) * 1024 + koff1);
      }
#pragma unroll
      for (int n = 0; n < 4; ++n)
        b1[n] = *reinterpret_cast<const bf16x8*>(Bc + brow0 + n * 1024 + koff1);
      __builtin_amdgcn_s_barrier();
      asm volatile("s_waitcnt lgkmcnt(0)" ::: "memory");
      __builtin_amdgcn_s_setprio(1);
#pragma unroll
      for (int m = 0; m < 4; ++m)
#pragma unroll
        for (int n = 0; n < 4; ++n)
          acc[m + 4][n] = __builtin_amdgcn_mfma_f32_16x16x32_bf16(a2K0[m], b0[n], acc[m + 4][n], 0, 0, 0);
      __builtin_amdgcn_s_setprio(0);
      __builtin_amdgcn_s_barrier();
    }
    // P3: stage A(t+2) half0; MFMA m0-3 x k1
    if (kt + 2 < NT) stageA2(cur, kt + 2, 0);
    __builtin_amdgcn_s_barrier();
    __builtin_amdgcn_s_setprio(1);
#pragma unroll
    for (int m = 0; m < 4; ++m)
#pragma unroll
      for (int n = 0; n < 4; ++n)
        acc[m][n] = __builtin_amdgcn_mfma_f32_16x16x32_bf16(aK1[m], b1[n], acc[m][n], 0, 0, 0);
    __builtin_amdgcn_s_setprio(0);
    __builtin_amdgcn_s_barrier();
    // P4: stage A(t+2) half1; MFMA m4-7 x k1; counted vmcnt
    if (kt + 2 < NT) stageA2(cur, kt + 2, 1);
    __builtin_amdgcn_s_barrier();
    __builtin_amdgcn_s_setprio(1);
#pragma unroll
    for (int m = 0; m < 4; ++m)
#pragma unroll
      for (int n = 0; n < 4; ++n)
        acc[m + 4][n] = __builtin_amdgcn_mfma_f32_16x16x32_bf16(a2K1[m], b1[n], acc[m + 4][n], 0, 0, 0);
    __builtin_amdgcn_s_setprio(0);
    if (kt < NT - 2) { asm volatile("s_waitcnt vmcnt(4)" ::: "memory"); }
    else             { asm volatile("s_waitcnt vmcnt(0)" ::: "memory"); }
    __builtin_amdgcn_s_barrier();
  }

  // epilogue: row = m0 + wr*128 + m*16 + lhi*4 + r ; col = n0 + wc*64 + n*16 + l15
  const int rb = wr * 128 + lhi * 4;
  const int cb = wc * 64 + l15;
  if (MODE == 0) {
#pragma unroll
    for (int n = 0; n < 4; ++n) {
      const int e = n0 + cb + n * 16;
      const int which = e >> 11;
      const int h = (e >> 7) & 15;
      const int d = e & 127;
      u16* dst = (which == 0) ? q_out : (which == 1) ? k_out : v_out;
#pragma unroll
      for (int m = 0; m < 8; ++m)
#pragma unroll
        for (int r = 0; r < 4; ++r) {
          const int bt = m0 + rb + m * 16 + r;
          const int bb = bt >> 11, tt = bt & 2047;
          dst[((size_t)(bb * 16 + h) * 2048 + tt) * 128 + d] = f2bf(acc[m][n][r]);
        }
    }
  } else {
#pragma unroll
    for (int m = 0; m < 8; ++m)
#pragma unroll
      for (int r = 0; r < 4; ++r) {
        const int row = m0 + rb + m * 16 + r;
#pragma unroll
        for (int n = 0; n < 4; ++n)
          f_out[(size_t)row * n_out + n0 + cb + n * 16] = acc[m][n][r];
      }
  }
}

// ---------------- m97-structure 128x128 GEMM (out-projection) ----------------
__global__ __launch_bounds__(256) void gemm_bt_kernel(
    const u16* __restrict__ A, const u16* __restrict__ Bw, int Kdim, int n_out,
    float* __restrict__ f_out)
{
  __shared__ __align__(16) u16 Asl[128 * 32];
  __shared__ __align__(16) u16 Bsl[128 * 32];
  const int t = threadIdx.x;
  const int lane = t & 63;
  const int w = t >> 6;
  const int wr = w >> 1, wc = w & 1;
  const int m0 = blockIdx.x * 128, n0 = blockIdx.y * 128;

  f32x4 acc[4][4];
#pragma unroll
  for (int m = 0; m < 4; ++m)
#pragma unroll
    for (int n = 0; n < 4; ++n)
#pragma unroll
      for (int i = 0; i < 4; ++i) acc[m][n][i] = 0.0f;

  const int ob0 = w * 1024 + lane * 16;
  const int row0 = ob0 >> 6;
  const int cole0 = (ob0 & 63) >> 1;
  const u16* gA0 = A + (size_t)(m0 + row0) * Kdim + cole0;
  const u16* gA1 = gA0 + (size_t)64 * Kdim;
  const u16* gB0 = Bw + (size_t)(n0 + row0) * Kdim + cole0;
  const u16* gB1 = gB0 + (size_t)64 * Kdim;
  u16* lA = Asl + w * 512;
  u16* lB = Bsl + w * 512;

  const int l15 = lane & 15;
  const int kb = (lane >> 4) * 8;

  for (int k0 = 0; k0 < Kdim; k0 += 32) {
    __syncthreads();
    gld_lds16(gA0, lA);
    gld_lds16(gA1, lA + 2048);
    gld_lds16(gB0, lB);
    gld_lds16(gB1, lB + 2048);
    gA0 += 32; gA1 += 32; gB0 += 32; gB1 += 32;
    __syncthreads();
    bf16x8 a[4], b[4];
#pragma unroll
    for (int m = 0; m < 4; ++m)
      a[m] = *reinterpret_cast<const bf16x8*>(Asl + (wr * 64 + m * 16 + l15) * 32 + kb);
#pragma unroll
    for (int n = 0; n < 4; ++n)
      b[n] = *reinterpret_cast<const bf16x8*>(Bsl + (wc * 64 + n * 16 + l15) * 32 + kb);
#pragma unroll
    for (int m = 0; m < 4; ++m)
#pragma unroll
      for (int n = 0; n < 4; ++n)
        acc[m][n] = __builtin_amdgcn_mfma_f32_16x16x32_bf16(a[m], b[n], acc[m][n], 0, 0, 0);
  }

  const int rb = wr * 64 + ((lane >> 4) << 2);
  const int cbs = wc * 64 + l15;
#pragma unroll
  for (int m = 0; m < 4; ++m)
#pragma unroll
    for (int r = 0; r < 4; ++r) {
      const int row = m0 + rb + m * 16 + r;
#pragma unroll
      for (int n = 0; n < 4; ++n)
        f_out[(size_t)row * n_out + n0 + cbs + n * 16] = acc[m][n][r];
    }
}

// ---------------- V transpose: (bh, t, d) -> (bh, d, t) ----------------
__global__ void transpose_v_kernel(const u16* __restrict__ V, u16* __restrict__ Vt) {
  __shared__ u16 tile[64][65];
  const int d0 = blockIdx.x * 64;
  const int t0 = blockIdx.y * 64;
  const int bh = blockIdx.z;
  const u16* src = V + (size_t)bh * (2048 * 128);
  u16* dst = Vt + (size_t)bh * (128 * 2048);
  const int tid = threadIdx.x;
  const int c4 = (tid & 15) * 4;
  const int r0 = tid >> 4;
#pragma unroll
  for (int p = 0; p < 4; ++p) {
    const int row = r0 + p * 16;
    const u16x4 v = *reinterpret_cast<const u16x4*>(src + (size_t)(t0 + row) * 128 + d0 + c4);
    tile[row][c4] = v[0]; tile[row][c4 + 1] = v[1];
    tile[row][c4 + 2] = v[2]; tile[row][c4 + 3] = v[3];
  }
  __syncthreads();
#pragma unroll
  for (int p = 0; p < 4; ++p) {
    const int dr = r0 + p * 16;
    u16x4 ov;
    ov[0] = tile[c4][dr]; ov[1] = tile[c4 + 1][dr];
    ov[2] = tile[c4 + 2][dr]; ov[3] = tile[c4 + 3][dr];
    *reinterpret_cast<u16x4*>(dst + (size_t)(d0 + dr) * 2048 + t0 + c4) = ov;
  }
}

// ---------------- flash attention, LDS-staged K/V, double-buffered, load-balanced ----------------
// (round-2/6 proven version: two sequential q-tile passes per block, 80 VGPR)
__global__ __launch_bounds__(256) void attn_kernel(
    const u16* __restrict__ Q, const u16* __restrict__ K,
    const u16* __restrict__ Vt, u16* __restrict__ O)
{
  __shared__ __align__(16) u16 k_lds[2][64 * 128];
  __shared__ __align__(16) u16 v_lds[2][128 * 64];
  __shared__ __align__(16) u16 p_lds[4][1024];
  const int t = threadIdx.x, lane = t & 63, w = t >> 6;
  const int bh = blockIdx.y;
  const int bx = blockIdx.x;
  const int l15 = lane & 15, lhi = lane >> 4;
  const size_t qkb = (size_t)bh * (2048 * 128);
  const u16* Kg = K + qkb;
  const u16* Vg = Vt + (size_t)bh * (size_t)(128 * 2048);
  char* pw = (char*)(&p_lds[w][0]);
  const int bb = bh >> 4, h = bh & 15;
  const int kxor = (l15 & 7) << 4;

  auto stage = [&](int buf, int k0) {
#pragma unroll
    for (int ii = 0; ii < 4; ++ii) {
      const int i = w * 4 + ii;
      const int krow = i * 4 + lhi;
      gld_lds16(Kg + (size_t)(k0 + krow) * 128 + (size_t)((l15 ^ (krow & 7)) * 8),
                &k_lds[buf][i * 512]);
    }
#pragma unroll
    for (int ii = 0; ii < 4; ++ii) {
      const int i = w * 4 + ii;
      const int vrow = i * 8 + (lane >> 3);
      gld_lds16(Vg + (size_t)vrow * 2048 + k0 + (size_t)(((lane & 7) ^ (vrow & 7)) * 8),
                &v_lds[buf][i * 512]);
    }
  };

  for (int half = 0; half < 2; ++half) {
    const int qt = half ? (31 - bx) : bx;
    const int q0 = qt * 64 + w * 16;
    bf16x8 aq[4];
    {
      const u16* qp = Q + qkb + (size_t)(q0 + l15) * 128 + lhi * 8;
#pragma unroll
      for (int ks = 0; ks < 4; ++ks) aq[ks] = *reinterpret_cast<const bf16x8*>(qp + ks * 32);
    }
    f32x4 o[8];
#pragma unroll
    for (int dt = 0; dt < 8; ++dt)
#pragma unroll
      for (int i = 0; i < 4; ++i) o[dt][i] = 0.0f;
    float mrow[4] = {-1e30f, -1e30f, -1e30f, -1e30f};
    float lrow[4] = {0.f, 0.f, 0.f, 0.f};
    const int rbase = q0 + (lhi << 2);
    const int ktmax = qt;

    __syncthreads();
    stage(0, 0);
    int cur = 0;
    for (int kt = 0; kt <= ktmax; ++kt) {
      __syncthreads();
      if (kt < ktmax) stage(cur ^ 1, (kt + 1) * 64);

      const char* kbb = (const char*)(&k_lds[cur][0]);
      f32x4 s4[4];
#pragma unroll
      for (int nt = 0; nt < 4; ++nt)
#pragma unroll
        for (int i = 0; i < 4; ++i) s4[nt][i] = 0.0f;
#pragma unroll
      for (int nt = 0; nt < 4; ++nt) {
        const int krow = nt * 16 + l15;
#pragma unroll
        for (int ks = 0; ks < 4; ++ks) {
          const bf16x8 bk = *reinterpret_cast<const bf16x8*>(
              kbb + krow * 256 + ((ks * 64 + lhi * 16) ^ kxor));
          s4[nt] = __builtin_amdgcn_mfma_f32_16x16x32_bf16(aq[ks], bk, s4[nt], 0, 0, 0);
        }
      }
      if (kt == ktmax) {
#pragma unroll
        for (int nt = 0; nt < 4; ++nt) {
          const int col = kt * 64 + nt * 16 + l15;
#pragma unroll
          for (int r = 0; r < 4; ++r)
            if (col > rbase + r) s4[nt][r] = -1e30f;
        }
      }
      float alpha[4];
#pragma unroll
      for (int r = 0; r < 4; ++r) {
        float mx = fmaxf(fmaxf(s4[0][r], s4[1][r]), fmaxf(s4[2][r], s4[3][r]));
        mx = fmaxf(mx, __shfl_xor(mx, 1));
        mx = fmaxf(mx, __shfl_xor(mx, 2));
        mx = fmaxf(mx, __shfl_xor(mx, 4));
        mx = fmaxf(mx, __shfl_xor(mx, 8));
        const float mn = fmaxf(mrow[r], mx);
        alpha[r] = __expf(mrow[r] - mn);
        mrow[r] = mn;
      }
      float ps[4] = {0.f, 0.f, 0.f, 0.f};
#pragma unroll
      for (int nt = 0; nt < 4; ++nt)
#pragma unroll
        for (int r = 0; r < 4; ++r) {
          const float p = __expf(s4[nt][r] - mrow[r]);
          ps[r] += p;
          const int prow = (lhi << 2) + r;
          const int cbyte = (nt * 16 + l15) * 2;
          *(u16*)(pw + prow * 128 + (cbyte ^ ((prow & 7) << 4))) = f2bf(p);
        }
#pragma unroll
      for (int r = 0; r < 4; ++r) {
        float rs = ps[r];
        rs += __shfl_xor(rs, 1);
        rs += __shfl_xor(rs, 2);
        rs += __shfl_xor(rs, 4);
        rs += __shfl_xor(rs, 8);
        lrow[r] = lrow[r] * alpha[r] + rs;
#pragma unroll
        for (int dt = 0; dt < 8; ++dt) o[dt][r] *= alpha[r];
      }
      const char* vbb = (const char*)(&v_lds[cur][0]);
#pragma unroll
      for (int ks2 = 0; ks2 < 2; ++ks2) {
        const bf16x8 ap = *reinterpret_cast<const bf16x8*>(
            pw + l15 * 128 + ((ks2 * 64 + (lhi << 4)) ^ kxor));
#pragma unroll
        for (int dt = 0; dt < 8; ++dt) {
          const int vrow = dt * 16 + l15;
          const bf16x8 bv = *reinterpret_cast<const bf16x8*>(
              vbb + vrow * 128 + ((ks2 * 64 + lhi * 16) ^ kxor));
          o[dt] = __builtin_amdgcn_mfma_f32_16x16x32_bf16(ap, bv, o[dt], 0, 0, 0);
        }
      }
      cur ^= 1;
    }
#pragma unroll
    for (int r = 0; r < 4; ++r) {
      const float inv = 1.0f / lrow[r];
      const int row = rbase + r;
      u16* op = O + (size_t)(bb * 2048 + row) * 2048 + h * 128 + l15;
#pragma unroll
      for (int dt = 0; dt < 8; ++dt) op[dt * 16] = f2bf(o[dt][r] * inv);
    }
  }
}

extern "C" void kernel_launch(void* const* d_in, const int* in_sizes, int n_in,
                              void* d_out, int out_size, void* d_ws, size_t ws_size,
                              hipStream_t stream) {
  const float* x = (const float*)d_in[0];      // (2,2048,2048) f32
  const float* wqkv = (const float*)d_in[1];   // (6144,2048) f32
  const float* wo = (const float*)d_in[2];     // (2048,2048) f32
  float* out = (float*)d_out;                  // (2,2048,2048) f32
  u16* ws = (u16*)d_ws;

  u16* xb = ws;                    // 8,388,608 elems
  u16* wqkvb = xb + 8388608;       // 12,582,912 (rotary-folded Q/K rows + plain V rows)
  u16* wob = wqkvb + 12582912;     // 4,194,304
  u16* Qb = wob + 4194304;         // 8,388,608
  u16* Kb = Qb + 8388608;          // 8,388,608
  u16* Vb = Kb + 8388608;          // 8,388,608  (total ~100.7 MB)
  u16* Vtb = wqkvb;                // alias: wqkvb dead after QKV GEMM
  u16* attn = xb;                  // alias: xb dead after QKV GEMM

  cvt_bf16_kernel<<<8192, 256, 0, stream>>>(x, xb, 2097152);
  rotw_kernel<<<4096, 256, 0, stream>>>(wqkv, wqkvb);
  cvt_bf16_kernel<<<4096, 256, 0, stream>>>(wqkv + (size_t)4096 * 2048,
                                            wqkvb + (size_t)4096 * 2048, 1048576);
  cvt_bf16_kernel<<<4096, 256, 0, stream>>>(wo, wob, 1048576);

  // QKV: M=4096, N=6144, K=2048 -> scatter to Q/K/V (B,H,T,dk) bf16 (rotary pre-folded)
  gemm8p_kernel<0><<<dim3(16, 24), 512, 0, stream>>>(xb, wqkvb, 2048, 0, Qb, Kb, Vb, nullptr);

  transpose_v_kernel<<<dim3(2, 32, 32), 256, 0, stream>>>(Vb, Vtb);

  attn_kernel<<<dim3(16, 32), 256, 0, stream>>>(Qb, Kb, Vtb, attn);

  // Out proj: M=4096, N=2048, K=2048 -> f32 d_out
  gemm_bt_kernel<<<dim3(32, 16), 256, 0, stream>>>(attn, wob, 2048, 2048, out);
}

// Round 10
// 309.666 us; speedup vs baseline: 1.6869x; 1.0076x over previous
//
#include <hip/hip_runtime.h>

typedef unsigned short u16;
typedef short bf16x8 __attribute__((ext_vector_type(8)));
typedef float f32x4 __attribute__((ext_vector_type(4)));
typedef unsigned short u16x4 __attribute__((ext_vector_type(4)));

// B=2, T=2048, D=2048, H=16, dk=128, BH=32, M=B*T=4096
#define QK_SCALE 0.08838834764831845f

__device__ __forceinline__ u16 f2bf(float f) {
  unsigned u = __float_as_uint(f);
  u += 0x7fffu + ((u >> 16) & 1u);
  return (u16)(u >> 16);
}
__device__ __forceinline__ float bf2f(u16 h) { return __uint_as_float(((unsigned)h) << 16); }

__device__ __forceinline__ void gld_lds16(const u16* g, u16* l) {
  __builtin_amdgcn_global_load_lds(
      (const __attribute__((address_space(1))) void*)g,
      (__attribute__((address_space(3))) void*)l, 16, 0, 0);
}

// ---------------- f32 -> bf16 convert ----------------
__global__ void cvt_bf16_kernel(const float* __restrict__ in, u16* __restrict__ out, int n4) {
  int i = blockIdx.x * 256 + threadIdx.x;
  if (i >= n4) return;
  const float4 v = reinterpret_cast<const float4*>(in)[i];
  u16x4 o;
  o[0] = f2bf(v.x); o[1] = f2bf(v.y); o[2] = f2bf(v.z); o[3] = f2bf(v.w);
  reinterpret_cast<u16x4*>(out)[i] = o;
}

// ---------------- rotary folded into Q/K weight rows (bug-faithful: angle = h*freqs[j]) --------
__global__ void rotw_kernel(const float* __restrict__ w, u16* __restrict__ wb) {
  const int i = blockIdx.x * 256 + threadIdx.x;   // which(2)*h(16)*j(64)*k4(512)
  const int k4 = i & 511;
  const int j = (i >> 9) & 63;
  const int h = (i >> 15) & 15;
  const int which = i >> 19;                       // 0=Q, 1=K
  const size_t e1 = (size_t)which * 2048 + h * 128 + j;
  const size_t e2 = e1 + 64;
  const float fr = (j < 32) ? __expf(-0.2971077539f * (float)j) : 0.0f;  // (1e-4)^(j/31)
  float s, c;
  __sincosf((float)h * fr, &s, &c);
  const float scale = (which == 0) ? QK_SCALE : 1.0f;
  const float4 a = reinterpret_cast<const float4*>(w + e1 * 2048)[k4];
  const float4 b = reinterpret_cast<const float4*>(w + e2 * 2048)[k4];
  u16x4 o1, o2;
  o1[0] = f2bf((a.x * c + b.x * s) * scale);
  o1[1] = f2bf((a.y * c + b.y * s) * scale);
  o1[2] = f2bf((a.z * c + b.z * s) * scale);
  o1[3] = f2bf((a.w * c + b.w * s) * scale);
  o2[0] = f2bf((b.x * c - a.x * s) * scale);
  o2[1] = f2bf((b.y * c - a.y * s) * scale);
  o2[2] = f2bf((b.z * c - a.z * s) * scale);
  o2[3] = f2bf((b.w * c - a.w * s) * scale);
  reinterpret_cast<u16x4*>(wb + e1 * 2048)[k4] = o1;
  reinterpret_cast<u16x4*>(wb + e2 * 2048)[k4] = o2;
}

// ================= 256x256 8-phase GEMM (round-3/6 proven config), C=A*Bw^T =================
template<int MODE>
__global__ __launch_bounds__(512, 2) void gemm8p_kernel(
    const u16* __restrict__ A, const u16* __restrict__ Bw, int Kdim, int n_out,
    u16* __restrict__ q_out, u16* __restrict__ k_out, u16* __restrict__ v_out,
    float* __restrict__ f_out)
{
  __shared__ __align__(16) u16 As[2][256 * 64];
  __shared__ __align__(16) u16 Bs[2][256 * 64];
  const int t = threadIdx.x, lane = t & 63, w = t >> 6;
  const int wr = w >> 2, wc = w & 3;
  const int l15 = lane & 15, lhi = lane >> 4;
  const int m0 = blockIdx.x * 256, n0 = blockIdx.y * 256;
  const int NT = Kdim >> 6;

  const int srow = w * 8 + (lane >> 3);
  const int gchunk = (lane & 7) ^ (srow & 7);
  const size_t gcol = (size_t)gchunk * 8;

  auto stageA2 = [&](int buf, int kt2, int half) {
    const size_t kb = (size_t)kt2 * 64 + gcol;
#pragma unroll
    for (int i = 0; i < 2; ++i) {
      const int ro = half * 128 + i * 64;
      gld_lds16(A + (size_t)(m0 + srow + ro) * Kdim + kb, &As[buf][(w * 8 + ro) * 64]);
    }
  };
  auto stageB4 = [&](int buf, int kt2) {
    const size_t kb = (size_t)kt2 * 64 + gcol;
#pragma unroll
    for (int ro = 0; ro < 256; ro += 64)
      gld_lds16(Bw + (size_t)(n0 + srow + ro) * Kdim + kb, &Bs[buf][(w * 8 + ro) * 64]);
  };

  const int arow0 = (wr * 128 + l15) * 64;
  const int brow0 = (wc * 64 + l15) * 64;
  const int koff0 = ((0 + lhi) ^ (l15 & 7)) * 8;
  const int koff1 = ((4 + lhi) ^ (l15 & 7)) * 8;

  f32x4 acc[8][4];
#pragma unroll
  for (int m = 0; m < 8; ++m)
#pragma unroll
    for (int n = 0; n < 4; ++n)
#pragma unroll
      for (int i = 0; i < 4; ++i) acc[m][n][i] = 0.0f;

  stageA2(0, 0, 0); stageA2(0, 0, 1);
  stageB4(0, 0);
  if (NT > 1) { stageA2(1, 1, 0); stageA2(1, 1, 1); }
  asm volatile("s_waitcnt vmcnt(4)" ::: "memory");
  __builtin_amdgcn_s_barrier();

  for (int kt = 0; kt < NT; ++kt) {
    const int cur = kt & 1;
    const u16* __restrict__ Ac = &As[cur][0];
    const u16* __restrict__ Bc = &Bs[cur][0];
    bf16x8 aK1[4], a2K1[4], b0[4], b1[4];
    // P1: read A[m0-3] k0+k1, B k0; stage B(t+1); MFMA m0-3 x k0
    {
      bf16x8 aK0[4];
#pragma unroll
      for (int m = 0; m < 4; ++m) {
        aK0[m] = *reinterpret_cast<const bf16x8*>(Ac + arow0 + m * 1024 + koff0);
        aK1[m] = *reinterpret_cast<const bf16x8*>(Ac + arow0 + m * 1024 + koff1);
      }
#pragma unroll
      for (int n = 0; n < 4; ++n)
        b0[n] = *reinterpret_cast<const bf16x8*>(Bc + brow0 + n * 1024 + koff0);
      if (kt + 1 < NT) stageB4(cur ^ 1, kt + 1);
      __builtin_amdgcn_s_barrier();
      asm volatile("s_waitcnt lgkmcnt(0)" ::: "memory");
      __builtin_amdgcn_s_setprio(1);
#pragma unroll
      for (int m = 0; m < 4; ++m)
#pragma unroll
        for (int n = 0; n < 4; ++n)
          acc[m][n] = __builtin_amdgcn_mfma_f32_16x16x32_bf16(aK0[m], b0[n], acc[m][n], 0, 0, 0);
      __builtin_amdgcn_s_setprio(0);
      __builtin_amdgcn_s_barrier();
    }
    // P2: read A[m4-7] k0+k1, B k1; MFMA m4-7 x k0
    {
      bf16x8 a2K0[4];
#pragma unroll
      for (int m = 0; m < 4; ++m) {
        a2K0[m] = *reinterpret_cast<const bf16x8*>(Ac + arow0 + (m + 4) * 1024 + koff0);
        a2K1[m] = *reinterpret_cast<const bf16x8*>(Ac + arow0 + (m + 4) * 1024 + koff1);
      }
#pragma unroll
      for (int n = 0; n < 4; ++n)
        b1[n] = *reinterpret_cast<const bf16x8*>(Bc + brow0 + n * 1024 + koff1);
      __builtin_amdgcn_s_barrier();
      asm volatile("s_waitcnt lgkmcnt(0)" ::: "memory");
      __builtin_amdgcn_s_setprio(1);
#pragma unroll
      for (int m = 0; m < 4; ++m)
#pragma unroll
        for (int n = 0; n < 4; ++n)
          acc[m + 4][n] = __builtin_amdgcn_mfma_f32_16x16x32_bf16(a2K0[m], b0[n], acc[m + 4][n], 0, 0, 0);
      __builtin_amdgcn_s_setprio(0);
      __builtin_amdgcn_s_barrier();
    }
    // P3: stage A(t+2) half0; MFMA m0-3 x k1
    if (kt + 2 < NT) stageA2(cur, kt + 2, 0);
    __builtin_amdgcn_s_barrier();
    __builtin_amdgcn_s_setprio(1);
#pragma unroll
    for (int m = 0; m < 4; ++m)
#pragma unroll
      for (int n = 0; n < 4; ++n)
        acc[m][n] = __builtin_amdgcn_mfma_f32_16x16x32_bf16(aK1[m], b1[n], acc[m][n], 0, 0, 0);
    __builtin_amdgcn_s_setprio(0);
    __builtin_amdgcn_s_barrier();
    // P4: stage A(t+2) half1; MFMA m4-7 x k1; counted vmcnt
    if (kt + 2 < NT) stageA2(cur, kt + 2, 1);
    __builtin_amdgcn_s_barrier();
    __builtin_amdgcn_s_setprio(1);
#pragma unroll
    for (int m = 0; m < 4; ++m)
#pragma unroll
      for (int n = 0; n < 4; ++n)
        acc[m + 4][n] = __builtin_amdgcn_mfma_f32_16x16x32_bf16(a2K1[m], b1[n], acc[m + 4][n], 0, 0, 0);
    __builtin_amdgcn_s_setprio(0);
    if (kt < NT - 2) { asm volatile("s_waitcnt vmcnt(4)" ::: "memory"); }
    else             { asm volatile("s_waitcnt vmcnt(0)" ::: "memory"); }
    __builtin_amdgcn_s_barrier();
  }

  // epilogue: row = m0 + wr*128 + m*16 + lhi*4 + r ; col = n0 + wc*64 + n*16 + l15
  const int rb = wr * 128 + lhi * 4;
  const int cb = wc * 64 + l15;
  if (MODE == 0) {
#pragma unroll
    for (int n = 0; n < 4; ++n) {
      const int e = n0 + cb + n * 16;
      const int which = e >> 11;
      const int h = (e >> 7) & 15;
      const int d = e & 127;
      u16* dst = (which == 0) ? q_out : (which == 1) ? k_out : v_out;
#pragma unroll
      for (int m = 0; m < 8; ++m)
#pragma unroll
        for (int r = 0; r < 4; ++r) {
          const int bt = m0 + rb + m * 16 + r;
          const int bb = bt >> 11, tt = bt & 2047;
          dst[((size_t)(bb * 16 + h) * 2048 + tt) * 128 + d] = f2bf(acc[m][n][r]);
        }
    }
  } else {
#pragma unroll
    for (int m = 0; m < 8; ++m)
#pragma unroll
      for (int r = 0; r < 4; ++r) {
        const int row = m0 + rb + m * 16 + r;
#pragma unroll
        for (int n = 0; n < 4; ++n)
          f_out[(size_t)row * n_out + n0 + cb + n * 16] = acc[m][n][r];
      }
  }
}

// ---------------- m97-structure 128x128 GEMM (out-projection) ----------------
__global__ __launch_bounds__(256) void gemm_bt_kernel(
    const u16* __restrict__ A, const u16* __restrict__ Bw, int Kdim, int n_out,
    float* __restrict__ f_out)
{
  __shared__ __align__(16) u16 Asl[128 * 32];
  __shared__ __align__(16) u16 Bsl[128 * 32];
  const int t = threadIdx.x;
  const int lane = t & 63;
  const int w = t >> 6;
  const int wr = w >> 1, wc = w & 1;
  const int m0 = blockIdx.x * 128, n0 = blockIdx.y * 128;

  f32x4 acc[4][4];
#pragma unroll
  for (int m = 0; m < 4; ++m)
#pragma unroll
    for (int n = 0; n < 4; ++n)
#pragma unroll
      for (int i = 0; i < 4; ++i) acc[m][n][i] = 0.0f;

  const int ob0 = w * 1024 + lane * 16;
  const int row0 = ob0 >> 6;
  const int cole0 = (ob0 & 63) >> 1;
  const u16* gA0 = A + (size_t)(m0 + row0) * Kdim + cole0;
  const u16* gA1 = gA0 + (size_t)64 * Kdim;
  const u16* gB0 = Bw + (size_t)(n0 + row0) * Kdim + cole0;
  const u16* gB1 = gB0 + (size_t)64 * Kdim;
  u16* lA = Asl + w * 512;
  u16* lB = Bsl + w * 512;

  const int l15 = lane & 15;
  const int kb = (lane >> 4) * 8;

  for (int k0 = 0; k0 < Kdim; k0 += 32) {
    __syncthreads();
    gld_lds16(gA0, lA);
    gld_lds16(gA1, lA + 2048);
    gld_lds16(gB0, lB);
    gld_lds16(gB1, lB + 2048);
    gA0 += 32; gA1 += 32; gB0 += 32; gB1 += 32;
    __syncthreads();
    bf16x8 a[4], b[4];
#pragma unroll
    for (int m = 0; m < 4; ++m)
      a[m] = *reinterpret_cast<const bf16x8*>(Asl + (wr * 64 + m * 16 + l15) * 32 + kb);
#pragma unroll
    for (int n = 0; n < 4; ++n)
      b[n] = *reinterpret_cast<const bf16x8*>(Bsl + (wc * 64 + n * 16 + l15) * 32 + kb);
#pragma unroll
    for (int m = 0; m < 4; ++m)
#pragma unroll
      for (int n = 0; n < 4; ++n)
        acc[m][n] = __builtin_amdgcn_mfma_f32_16x16x32_bf16(a[m], b[n], acc[m][n], 0, 0, 0);
  }

  const int rb = wr * 64 + ((lane >> 4) << 2);
  const int cbs = wc * 64 + l15;
#pragma unroll
  for (int m = 0; m < 4; ++m)
#pragma unroll
    for (int r = 0; r < 4; ++r) {
      const int row = m0 + rb + m * 16 + r;
#pragma unroll
      for (int n = 0; n < 4; ++n)
        f_out[(size_t)row * n_out + n0 + cbs + n * 16] = acc[m][n][r];
    }
}

// ---------------- V transpose: (bh, t, d) -> (bh, d, t) ----------------
__global__ void transpose_v_kernel(const u16* __restrict__ V, u16* __restrict__ Vt) {
  __shared__ u16 tile[64][65];
  const int d0 = blockIdx.x * 64;
  const int t0 = blockIdx.y * 64;
  const int bh = blockIdx.z;
  const u16* src = V + (size_t)bh * (2048 * 128);
  u16* dst = Vt + (size_t)bh * (128 * 2048);
  const int tid = threadIdx.x;
  const int c4 = (tid & 15) * 4;
  const int r0 = tid >> 4;
#pragma unroll
  for (int p = 0; p < 4; ++p) {
    const int row = r0 + p * 16;
    const u16x4 v = *reinterpret_cast<const u16x4*>(src + (size_t)(t0 + row) * 128 + d0 + c4);
    tile[row][c4] = v[0]; tile[row][c4 + 1] = v[1];
    tile[row][c4 + 2] = v[2]; tile[row][c4 + 3] = v[3];
  }
  __syncthreads();
#pragma unroll
  for (int p = 0; p < 4; ++p) {
    const int dr = r0 + p * 16;
    u16x4 ov;
    ov[0] = tile[c4][dr]; ov[1] = tile[c4 + 1][dr];
    ov[2] = tile[c4 + 2][dr]; ov[3] = tile[c4 + 3][dr];
    *reinterpret_cast<u16x4*>(dst + (size_t)(d0 + dr) * 2048 + t0 + c4) = ov;
  }
}

// ---------------- flash attention, LDS-staged K/V, double-buffered, load-balanced ----------------
// round-6 structure + T5 setprio around MFMA clusters + T13 defer-max (THR=8, wave-uniform skip)
__global__ __launch_bounds__(256) void attn_kernel(
    const u16* __restrict__ Q, const u16* __restrict__ K,
    const u16* __restrict__ Vt, u16* __restrict__ O)
{
  __shared__ __align__(16) u16 k_lds[2][64 * 128];
  __shared__ __align__(16) u16 v_lds[2][128 * 64];
  __shared__ __align__(16) u16 p_lds[4][1024];
  const int t = threadIdx.x, lane = t & 63, w = t >> 6;
  const int bh = blockIdx.y;
  const int bx = blockIdx.x;
  const int l15 = lane & 15, lhi = lane >> 4;
  const size_t qkb = (size_t)bh * (2048 * 128);
  const u16* Kg = K + qkb;
  const u16* Vg = Vt + (size_t)bh * (size_t)(128 * 2048);
  char* pw = (char*)(&p_lds[w][0]);
  const int bb = bh >> 4, h = bh & 15;
  const int kxor = (l15 & 7) << 4;

  auto stage = [&](int buf, int k0) {
#pragma unroll
    for (int ii = 0; ii < 4; ++ii) {
      const int i = w * 4 + ii;
      const int krow = i * 4 + lhi;
      gld_lds16(Kg + (size_t)(k0 + krow) * 128 + (size_t)((l15 ^ (krow & 7)) * 8),
                &k_lds[buf][i * 512]);
    }
#pragma unroll
    for (int ii = 0; ii < 4; ++ii) {
      const int i = w * 4 + ii;
      const int vrow = i * 8 + (lane >> 3);
      gld_lds16(Vg + (size_t)vrow * 2048 + k0 + (size_t)(((lane & 7) ^ (vrow & 7)) * 8),
                &v_lds[buf][i * 512]);
    }
  };

  for (int half = 0; half < 2; ++half) {
    const int qt = half ? (31 - bx) : bx;
    const int q0 = qt * 64 + w * 16;
    bf16x8 aq[4];
    {
      const u16* qp = Q + qkb + (size_t)(q0 + l15) * 128 + lhi * 8;
#pragma unroll
      for (int ks = 0; ks < 4; ++ks) aq[ks] = *reinterpret_cast<const bf16x8*>(qp + ks * 32);
    }
    f32x4 o[8];
#pragma unroll
    for (int dt = 0; dt < 8; ++dt)
#pragma unroll
      for (int i = 0; i < 4; ++i) o[dt][i] = 0.0f;
    float mrow[4] = {-1e30f, -1e30f, -1e30f, -1e30f};
    float lrow[4] = {0.f, 0.f, 0.f, 0.f};
    const int rbase = q0 + (lhi << 2);
    const int ktmax = qt;

    __syncthreads();
    stage(0, 0);
    int cur = 0;
    for (int kt = 0; kt <= ktmax; ++kt) {
      __syncthreads();
      if (kt < ktmax) stage(cur ^ 1, (kt + 1) * 64);

      const char* kbb = (const char*)(&k_lds[cur][0]);
      f32x4 s4[4];
#pragma unroll
      for (int nt = 0; nt < 4; ++nt)
#pragma unroll
        for (int i = 0; i < 4; ++i) s4[nt][i] = 0.0f;
      __builtin_amdgcn_s_setprio(1);
#pragma unroll
      for (int nt = 0; nt < 4; ++nt) {
        const int krow = nt * 16 + l15;
#pragma unroll
        for (int ks = 0; ks < 4; ++ks) {
          const bf16x8 bk = *reinterpret_cast<const bf16x8*>(
              kbb + krow * 256 + ((ks * 64 + lhi * 16) ^ kxor));
          s4[nt] = __builtin_amdgcn_mfma_f32_16x16x32_bf16(aq[ks], bk, s4[nt], 0, 0, 0);
        }
      }
      __builtin_amdgcn_s_setprio(0);
      if (kt == ktmax) {
#pragma unroll
        for (int nt = 0; nt < 4; ++nt) {
          const int col = kt * 64 + nt * 16 + l15;
#pragma unroll
          for (int r = 0; r < 4; ++r)
            if (col > rbase + r) s4[nt][r] = -1e30f;
        }
      }
      // row maxes (16-lane-group reduce)
      float mxv[4];
#pragma unroll
      for (int r = 0; r < 4; ++r) {
        float mx = fmaxf(fmaxf(s4[0][r], s4[1][r]), fmaxf(s4[2][r], s4[3][r]));
        mx = fmaxf(mx, __shfl_xor(mx, 1));
        mx = fmaxf(mx, __shfl_xor(mx, 2));
        mx = fmaxf(mx, __shfl_xor(mx, 4));
        mx = fmaxf(mx, __shfl_xor(mx, 8));
        mxv[r] = mx;
      }
      // T13 defer-max: skip m-update + O-rescale when growth <= 8 for ALL rows in wave
      const bool ok = (mxv[0] <= mrow[0] + 8.f) && (mxv[1] <= mrow[1] + 8.f) &&
                      (mxv[2] <= mrow[2] + 8.f) && (mxv[3] <= mrow[3] + 8.f);
      if (!__all(ok)) {
#pragma unroll
        for (int r = 0; r < 4; ++r) {
          const float mn = fmaxf(mrow[r], mxv[r]);
          const float alpha = __expf(mrow[r] - mn);
          mrow[r] = mn;
          lrow[r] *= alpha;
#pragma unroll
          for (int dt = 0; dt < 8; ++dt) o[dt][r] *= alpha;
        }
      }
      float ps[4] = {0.f, 0.f, 0.f, 0.f};
#pragma unroll
      for (int nt = 0; nt < 4; ++nt)
#pragma unroll
        for (int r = 0; r < 4; ++r) {
          const float p = __expf(s4[nt][r] - mrow[r]);
          ps[r] += p;
          const int prow = (lhi << 2) + r;
          const int cbyte = (nt * 16 + l15) * 2;
          *(u16*)(pw + prow * 128 + (cbyte ^ ((prow & 7) << 4))) = f2bf(p);
        }
#pragma unroll
      for (int r = 0; r < 4; ++r) {
        float rs = ps[r];
        rs += __shfl_xor(rs, 1);
        rs += __shfl_xor(rs, 2);
        rs += __shfl_xor(rs, 4);
        rs += __shfl_xor(rs, 8);
        lrow[r] += rs;
      }
      const char* vbb = (const char*)(&v_lds[cur][0]);
      __builtin_amdgcn_s_setprio(1);
#pragma unroll
      for (int ks2 = 0; ks2 < 2; ++ks2) {
        const bf16x8 ap = *reinterpret_cast<const bf16x8*>(
            pw + l15 * 128 + ((ks2 * 64 + (lhi << 4)) ^ kxor));
#pragma unroll
        for (int dt = 0; dt < 8; ++dt) {
          const int vrow = dt * 16 + l15;
          const bf16x8 bv = *reinterpret_cast<const bf16x8*>(
              vbb + vrow * 128 + ((ks2 * 64 + lhi * 16) ^ kxor));
          o[dt] = __builtin_amdgcn_mfma_f32_16x16x32_bf16(ap, bv, o[dt], 0, 0, 0);
        }
      }
      __builtin_amdgcn_s_setprio(0);
      cur ^= 1;
    }
#pragma unroll
    for (int r = 0; r < 4; ++r) {
      const float inv = 1.0f / lrow[r];
      const int row = rbase + r;
      u16* op = O + (size_t)(bb * 2048 + row) * 2048 + h * 128 + l15;
#pragma unroll
      for (int dt = 0; dt < 8; ++dt) op[dt * 16] = f2bf(o[dt][r] * inv);
    }
  }
}

extern "C" void kernel_launch(void* const* d_in, const int* in_sizes, int n_in,
                              void* d_out, int out_size, void* d_ws, size_t ws_size,
                              hipStream_t stream) {
  const float* x = (const float*)d_in[0];      // (2,2048,2048) f32
  const float* wqkv = (const float*)d_in[1];   // (6144,2048) f32
  const float* wo = (const float*)d_in[2];     // (2048,2048) f32
  float* out = (float*)d_out;                  // (2,2048,2048) f32
  u16* ws = (u16*)d_ws;

  u16* xb = ws;                    // 8,388,608 elems
  u16* wqkvb = xb + 8388608;       // 12,582,912 (rotary-folded Q/K rows + plain V rows)
  u16* wob = wqkvb + 12582912;     // 4,194,304
  u16* Qb = wob + 4194304;         // 8,388,608
  u16* Kb = Qb + 8388608;          // 8,388,608
  u16* Vb = Kb + 8388608;          // 8,388,608  (total ~100.7 MB)
  u16* Vtb = wqkvb;                // alias: wqkvb dead after QKV GEMM
  u16* attn = xb;                  // alias: xb dead after QKV GEMM

  cvt_bf16_kernel<<<8192, 256, 0, stream>>>(x, xb, 2097152);
  rotw_kernel<<<4096, 256, 0, stream>>>(wqkv, wqkvb);
  cvt_bf16_kernel<<<4096, 256, 0, stream>>>(wqkv + (size_t)4096 * 2048,
                                            wqkvb + (size_t)4096 * 2048, 1048576);
  cvt_bf16_kernel<<<4096, 256, 0, stream>>>(wo, wob, 1048576);

  // QKV: M=4096, N=6144, K=2048 -> scatter to Q/K/V (B,H,T,dk) bf16 (rotary pre-folded)
  gemm8p_kernel<0><<<dim3(16, 24), 512, 0, stream>>>(xb, wqkvb, 2048, 0, Qb, Kb, Vb, nullptr);

  transpose_v_kernel<<<dim3(2, 32, 32), 256, 0, stream>>>(Vb, Vtb);

  attn_kernel<<<dim3(16, 32), 256, 0, stream>>>(Qb, Kb, Vtb, attn);

  // Out proj: M=4096, N=2048, K=2048 -> f32 d_out
  gemm_bt_kernel<<<dim3(32, 16), 256, 0, stream>>>(attn, wob, 2048, 2048, out);
}